// Round 16
// baseline (332.290 us; speedup 1.0000x reference)
//
#include <hip/hip_runtime.h>
#include <hip/hip_bf16.h>

#define NPTS 8192
#define KNN 64
#define EPSF 1e-7f
#define BINW 0.075f
#define INVW (1.0f/0.075f)

// ---------------- workspace layout (float offsets) ----------------
#define OFF_P4      0              // packed (x,y,z,rr) float4 per point: 4*N
#define OFF_STATS   32768          // s1:+0(128) s2:+128(256) s3:+384(512) s4:+896(2048) = 2944
#define OFF_C       35712          // 64 u32 shell cursors (zeroed by prepwt)
#define OFF_PART    36012          // 32 blocks x 2 u64 = 128 floats
#define OFF_FEATDN  36864          // N*4 -> 69632 (raw-view source for conv1-on-the-fly)
#define OFF_WT1     69632          // 4*64 fp32 transposed -> 69888
#define OFF_GWT     69888          // MLP bf16 weights -> 79104
#define OFF_BW2     79104          // -> 83200
#define OFF_BW3     83200          // -> 107776
#define OFF_BW4     107776         // -> 238848
#define OFF_XB3V    238848         // bf16 raw-view emb_up [8192][64] -> 500992
#define OFF_P4S     501248         // shell-compacted float4[8192] -> 534016
#define OFF_IDXS    534016         // u32[8192] orig indices -> 542208
#define OFF_H32     542208         // u32[32][64] per-block shell hists -> 544256
#define OFF_POUT    544256         // u32[64] shell starts -> 544320
#define OFF_Y2      2860288        // 128*N fp32 channel-major -> 3908864
#define OFF_Y3      3908864        // 256*N fp32 channel-major -> 6006016
#define OFF_FEATUP  6006016        // N*K*4 fp32 -> 8103168

typedef __bf16 bf16x8 __attribute__((ext_vector_type(8)));
typedef float  f32x4  __attribute__((ext_vector_type(4)));

__device__ __forceinline__ unsigned f2u(float f) {
    unsigned u = __float_as_uint(f);
    return ((int)u >= 0) ? (u | 0x80000000u) : ~u;
}
__device__ __forceinline__ float key_to_f(unsigned long long k) {
    unsigned v = (unsigned)(k >> 32);
    unsigned ob = (v & 0x80000000u) ? (v ^ 0x80000000u) : ~v;
    return __uint_as_float(ob);
}
__device__ __forceinline__ unsigned short f2bf(float x) {
    union { __bf16 h; unsigned short s; } u;
    u.h = (__bf16)x;
    return u.s;
}
__device__ __forceinline__ unsigned packbf2(float lo, float hi) {
    return (unsigned)f2bf(lo) | ((unsigned)f2bf(hi) << 16);
}
__device__ __forceinline__ unsigned long long u64min(unsigned long long a, unsigned long long b){ return a < b ? a : b; }
__device__ __forceinline__ unsigned long long u64max(unsigned long long a, unsigned long long b){ return a < b ? b : a; }

__device__ __forceinline__ unsigned long long sort_merge(
    unsigned long long key, unsigned long long cur, int lane)
{
    #pragma unroll
    for (int k = 2; k <= 64; k <<= 1) {
        #pragma unroll
        for (int j = k >> 1; j > 0; j >>= 1) {
            unsigned long long o = __shfl_xor(key, j);
            bool up = ((lane & k) == 0);
            bool lower = ((lane & j) == 0);
            key = (lower == up) ? u64min(key, o) : u64max(key, o);
        }
    }
    unsigned long long rev = __shfl(key, 63 - lane);
    unsigned long long m = u64min(cur, rev);
    #pragma unroll
    for (int j = 32; j > 0; j >>= 1) {
        unsigned long long o = __shfl_xor(m, j);
        m = ((lane & j) == 0) ? u64min(m, o) : u64max(m, o);
    }
    return m;
}

// ---------------- prep A + weight prep (fused; disjoint work) ----------------
__global__ __launch_bounds__(256) void prepwt_kernel(
    const float* __restrict__ points,
    const float* __restrict__ c1w, const float* __restrict__ c2w,
    const float* __restrict__ c3w, const float* __restrict__ c4w,
    const float* __restrict__ gw0, const float* __restrict__ gw1,
    const float* __restrict__ gw2, const float* __restrict__ gw3,
    const float* __restrict__ gw4,
    float* __restrict__ ws)
{
    const int t = blockIdx.x * 256 + threadIdx.x;
    const int T = 256 * 256;
    for (int m = t; m < 2944; m += T) ws[OFF_STATS + m] = 0.f;
    for (int m = t; m < 64; m += T) ((unsigned*)(ws + OFF_C))[m] = 0u;   // shell cursors
    for (int m = t; m < 64*4; m += T) { int o = m >> 2, c = m & 3; ws[OFF_WT1 + c*64 + o] = c1w[m]; }

    unsigned short* bw2 = (unsigned short*)(ws + OFF_BW2);
    for (int m = t; m < 128*64; m += T)   bw2[m] = f2bf(c2w[m]);
    unsigned short* bw3 = (unsigned short*)(ws + OFF_BW3);
    for (int m = t; m < 256*192; m += T)  bw3[m] = f2bf(c3w[m]);
    unsigned short* bw4 = (unsigned short*)(ws + OFF_BW4);
    for (int m = t; m < 1024*256; m += T) bw4[m] = f2bf(c4w[m]);

    unsigned short* gwt = (unsigned short*)(ws + OFF_GWT);
    for (int m = t; m < 2048; m += T) {          // gw0T padded [64][32]
        int o = m >> 5, i = m & 31;
        gwt[m] = (i < 4) ? f2bf(gw0[i*64 + o]) : (unsigned short)0;
    }
    const float* gsrc[4] = {gw1, gw2, gw3, gw4};
    for (int l = 0; l < 4; ++l) {
        const float* g = gsrc[l];
        unsigned short* dst = gwt + 2048 + l*4096;
        for (int m = t; m < 4096; m += T) { int o = m >> 6, i = m & 63; dst[m] = f2bf(g[i*64 + o]); }
    }

    // ---- prep_a part (blocks 0..31 only; block-uniform branch) ----
    if (blockIdx.x < 32) {
        __shared__ unsigned lh[64];             // per-block shell histogram (race-free)
        if (threadIdx.x < 64) lh[threadIdx.x] = 0u;
        __syncthreads();
        const int n = blockIdx.x * 256 + threadIdx.x;
        float x = points[3*n+0], y = points[3*n+1], z = points[3*n+2];
        float rr = x*x + y*y + z*z;
        ((float4*)(ws + OFF_P4))[n] = make_float4(x, y, z, rr);
        float vn = sqrtf(rr);
        int bin = (int)(vn * INVW); if (bin > 63) bin = 63;
        atomicAdd(&lh[bin], 1u);
        unsigned b = __float_as_uint(vn);
        unsigned long long mxk = ((unsigned long long)b << 32) | (unsigned long long)(0xFFFFFFFFu - (unsigned)n);
        unsigned long long mnk = ((unsigned long long)b << 32) | (unsigned long long)(unsigned)n;
        for (int j = 32; j > 0; j >>= 1) {
            mxk = u64max(mxk, __shfl_xor(mxk, j));
            mnk = u64min(mnk, __shfl_xor(mnk, j));
        }
        __shared__ unsigned long long smx[4], smn[4];
        int wid = threadIdx.x >> 6;
        if ((threadIdx.x & 63) == 0) { smx[wid] = mxk; smn[wid] = mnk; }
        __syncthreads();
        if (threadIdx.x < 64)
            ((unsigned*)(ws + OFF_H32))[blockIdx.x * 64 + threadIdx.x] = lh[threadIdx.x];
        if (threadIdx.x == 0) {
            unsigned long long MX = 0ull, MN = ~0ull;
            for (int i = 0; i < 4; ++i) { MX = u64max(MX, smx[i]); MN = u64min(MN, smn[i]); }
            unsigned long long* parts = (unsigned long long*)(ws + OFF_PART);
            parts[2*blockIdx.x + 0] = MX;
            parts[2*blockIdx.x + 1] = MN;
        }
    }
}

// ---------------- scatter: shell-compact points (order within shell irrelevant) ----------------
__global__ __launch_bounds__(256) void scatter_kernel(float* __restrict__ ws)
{
    const int tid = threadIdx.x, lane = tid & 63;
    const unsigned* H32 = (const unsigned*)(ws + OFF_H32);
    unsigned h = 0;
    #pragma unroll
    for (int k = 0; k < 32; ++k) h += H32[k*64 + lane];
    // exclusive prefix over 64 lanes
    unsigned x = h;
    #pragma unroll
    for (int d = 1; d < 64; d <<= 1) { unsigned y = __shfl_up(x, d); if (lane >= d) x += y; }
    unsigned excl = x - h;

    const int n = blockIdx.x * 256 + tid;
    float4 v = ((const float4*)(ws + OFF_P4))[n];
    float vn = sqrtf(v.w);
    int bin = (int)(vn * INVW); if (bin > 63) bin = 63;
    unsigned base = (unsigned)__shfl((int)excl, bin);
    unsigned* C = (unsigned*)(ws + OFF_C);
    unsigned pos = base + atomicAdd(&C[bin], 1u);
    ((float4*)(ws + OFF_P4S))[pos] = v;
    ((unsigned*)(ws + OFF_IDXS))[pos] = (unsigned)n;
    if (blockIdx.x == 0 && tid < 64) ((unsigned*)(ws + OFF_POUT))[tid] = excl;
}

// ---------------- KNN via radial-shell pruning + features + feat_down ----------------
// 1 query/wave, 8 waves/block, LDS 8 KB (queue only). Exactness: admission threshold ke
// is conservative (only shrinks); shell pruning uses triangle inequality with fp margins;
// keys carry ORIGINAL indices -> bit-identical selection vs the full-scan version.
__global__ __launch_bounds__(512) void knn_feat_kernel(
    const float4* __restrict__ p4, const float4* __restrict__ p4s,
    const unsigned* __restrict__ idxs, float4* __restrict__ feat_up,
    float* __restrict__ ws)
{
    __shared__ unsigned long long queue[8][128];
    const int lane = threadIdx.x & 63;
    const int wid  = threadIdx.x >> 6;
    const int q = blockIdx.x * 8 + wid;

    const int pstart = (int)((const unsigned*)(ws + OFF_POUT))[lane];  // lane b: start of shell b

    const float4 qa = p4[q];
    const float qn = sqrtf(qa.w);
    unsigned long long cur = ~0ull;
    float ke = __builtin_inff();
    int qc = 0;
    unsigned long long* Q = queue[wid];

#define SCANB(BB) { \
    const int s_ = __shfl(pstart, (BB)); \
    const int e_ = ((BB) == 63) ? NPTS : __shfl(pstart, (BB) + 1); \
    for (int off = s_; off < e_; off += 64) { \
        const int jj = off + lane; \
        float e0 = __builtin_inff(); \
        float4 cd; \
        if (jj < e_) { \
            cd = p4s[jj]; \
            float dot = fmaf(qa.x, cd.x, fmaf(qa.y, cd.y, qa.z * cd.z)); \
            e0 = fmaf(-2.f, dot, cd.w); \
        } \
        bool p = e0 < ke; \
        unsigned long long m = __ballot(p); \
        if (m) { \
            int prefix = __builtin_amdgcn_mbcnt_hi((unsigned)(m >> 32), \
                          __builtin_amdgcn_mbcnt_lo((unsigned)m, 0)); \
            if (p) Q[qc + prefix] = ((unsigned long long)f2u(e0) << 32) \
                                  | (unsigned long long)idxs[jj]; \
            qc += __popcll(m); \
            if (qc >= 64) { \
                qc -= 64; \
                cur = sort_merge(Q[qc + lane], cur, lane); \
                ke = key_to_f(__shfl(cur, 63)); \
            } \
        } \
    } }

    int b0 = (int)(qn * INVW); if (b0 > 63) b0 = 63;
    int br = b0, bl = b0 - 1;
    bool rOK = true, lOK = (bl >= 0);
    while (rOK || lOK) {
        if (rOK) {
            if (br >= 64) rOK = false;
            else {
                bool go = true;
                if (br > b0) {
                    float d = br * BINW - qn;                    // lower bound on |p| gap
                    if (d > 0.f && d*d > fmaf(ke + qa.w, 1.0001f, 1e-4f)) go = false;
                }
                if (!go) rOK = false;
                else { SCANB(br); ++br; }
            }
        }
        if (lOK) {
            if (bl < 0) lOK = false;
            else {
                float d = qn - (bl + 1) * BINW;                  // upper bound of shell bl
                bool go = !(d > 0.f && d*d > fmaf(ke + qa.w, 1.0001f, 1e-4f));
                if (!go) lOK = false;
                else { SCANB(bl); --bl; }
            }
        }
    }
#undef SCANB
    cur = sort_merge((lane < qc) ? Q[lane] : ~0ull, cur, lane);

    // feature epilogue (feat_up) — identical to full-scan version
    int nidx = (int)(unsigned)(cur & 0xFFFFFFFFu);
    float4 np = p4[nidx];
    float ox = __shfl(np.x, 0), oy = __shfl(np.y, 0), oz = __shfl(np.z, 0);
    float pcx = np.x - ox, pcy = np.y - oy, pcz = np.z - oz;
    float vn = sqrtf(pcx*pcx + pcy*pcy + pcz*pcz);

    unsigned long long ak = ((unsigned long long)__float_as_uint(vn) << 32)
                          | (unsigned long long)(unsigned)(63 - lane);
    for (int s = 32; s > 0; s >>= 1) ak = u64max(ak, __shfl_xor(ak, s));
    int id1 = 63 - (int)(unsigned)(ak & 0xFFFFFFFFu);

    float a1x = __shfl(pcx, id1), a1y = __shfl(pcy, id1), a1z = __shfl(pcz, id1);
    float n1 = sqrtf(a1x*a1x + a1y*a1y + a1z*a1z) + EPSF;
    a1x /= n1; a1y /= n1; a1z /= n1;

    float sx = pcx, sy = pcy, sz = pcz;
    for (int s = 32; s > 0; s >>= 1) {
        sx += __shfl_xor(sx, s); sy += __shfl_xor(sy, s); sz += __shfl_xor(sz, s);
    }
    float a2x = sx * (1.f/64.f), a2y = sy * (1.f/64.f), a2z = sz * (1.f/64.f);
    float n2 = sqrtf(a2x*a2x + a2y*a2y + a2z*a2z) + EPSF;
    a2x /= n2; a2y /= n2; a2z /= n2;

    float a3x = a1x + 1.5f*a2x, a3y = a1y + 1.5f*a2y, a3z = a1z + 1.5f*a2z;
    float n3 = sqrtf(a3x*a3x + a3y*a3y + a3z*a3z) + EPSF;
    a3x /= n3; a3y /= n3; a3z /= n3;

    float den = vn + EPSF;
    float f1 = (pcx*a1x + pcy*a1y + pcz*a1z) / den;
    float f2 = (pcx*a2x + pcy*a2y + pcz*a2z) / den;
    float f3 = (pcx*a3x + pcy*a3y + pcz*a3z) / den;
    feat_up[q*64 + lane] = make_float4(f1, f2, f3, vn);

    // feat_down (prep_c folded): per-wave parts-reduce in registers, lane 0 writes.
    {
        const unsigned long long* parts = (const unsigned long long*)(ws + OFF_PART);
        unsigned long long mxk = (lane < 32) ? parts[2*lane + 0] : 0ull;
        unsigned long long mnk = (lane < 32) ? parts[2*lane + 1] : ~0ull;
        for (int s = 32; s > 0; s >>= 1) {
            mxk = u64max(mxk, __shfl_xor(mxk, s));
            mnk = u64min(mnk, __shfl_xor(mnk, s));
        }
        if (lane == 0) {
            int i1 = (int)(0xFFFFFFFFu - (unsigned)(mxk & 0xFFFFFFFFu));
            int i2 = (int)(unsigned)(mnk & 0xFFFFFFFFu);
            float4 p1 = p4[i1];
            float4 p2 = p4[i2];
            float w1 = sqrtf(p1.x*p1.x + p1.y*p1.y + p1.z*p1.z) + EPSF;
            float b1x = p1.x/w1, b1y = p1.y/w1, b1z = p1.z/w1;
            float w2 = sqrtf(p2.x*p2.x + p2.y*p2.y + p2.z*p2.z) + EPSF;
            float b2x = p2.x/w2, b2y = p2.y/w2, b2z = p2.z/w2;
            float b3x = b1x + 1.5f*b2x, b3y = b1y + 1.5f*b2y, b3z = b1z + 1.5f*b2z;
            float w3 = sqrtf(b3x*b3x + b3y*b3y + b3z*b3z) + EPSF;
            b3x /= w3; b3y /= w3; b3z /= w3;
            float vq = sqrtf(qa.w);
            float dq = vq + EPSF;
            float g1 = (qa.x*b1x + qa.y*b1y + qa.z*b1z) / dq;
            float g2 = (qa.x*b2x + qa.y*b2y + qa.z*b2z) / dq;
            float g3 = (qa.x*b3x + qa.y*b3y + qa.z*b3z) / dq;
            ((float4*)(ws + OFF_FEATDN))[q] = make_float4(g1, g2, g3, vq);
        }
    }
}

// ---------------- 5-layer MLP via bf16 MFMA + max over K + conv1-STATS side-job ----------------
#define BROW 72
__global__ __launch_bounds__(256) void mlp_kernel(
    const float4* __restrict__ feat_up,
    const unsigned short* __restrict__ gwt,
    unsigned short* __restrict__ xb3v,
    const float* __restrict__ c1b,
    float* __restrict__ ws)
{
    __shared__ __align__(16) unsigned short Blds[4][64 * BROW];
    const int lane = threadIdx.x & 63;
    const int wid  = threadIdx.x >> 6;
    const int q = blockIdx.x * 4 + wid;
    const int c = lane & 15, g = lane >> 4;
    unsigned short* B = Blds[wid];

    {
        float4 f = feat_up[q*64 + lane];
        uint2 p0;
        p0.x = packbf2(f.x, f.y);
        p0.y = packbf2(f.z, f.w);
        *(uint2*)&B[lane*BROW] = p0;
        *(uint2*)&B[lane*BROW + 4] = make_uint2(0, 0);
        uint4 z4 = make_uint4(0, 0, 0, 0);
        *(uint4*)&B[lane*BROW + 8]  = z4;
        *(uint4*)&B[lane*BROW + 16] = z4;
        *(uint4*)&B[lane*BROW + 24] = z4;
    }

    const unsigned short* Wl[5] = {gwt, gwt + 2048, gwt + 6144, gwt + 10240, gwt + 14336};
    f32x4 acc[4][4];

    for (int layer = 0; layer < 5; ++layer) {
        const int wstride = (layer == 0) ? 32 : 64;
        const int nks = (layer == 0) ? 1 : 2;
        #pragma unroll
        for (int mb = 0; mb < 4; ++mb)
            #pragma unroll
            for (int nb = 0; nb < 4; ++nb)
                acc[mb][nb] = (f32x4){0.f, 0.f, 0.f, 0.f};

        for (int ks = 0; ks < nks; ++ks) {
            bf16x8 af[4], bf[4];
            #pragma unroll
            for (int mb = 0; mb < 4; ++mb)
                af[mb] = *(const bf16x8*)(Wl[layer] + (mb*16 + c)*wstride + ks*32 + g*8);
            #pragma unroll
            for (int nb = 0; nb < 4; ++nb)
                bf[nb] = *(const bf16x8*)&B[(nb*16 + c)*BROW + ks*32 + g*8];
            #pragma unroll
            for (int mb = 0; mb < 4; ++mb)
                #pragma unroll
                for (int nb = 0; nb < 4; ++nb)
                    acc[mb][nb] = __builtin_amdgcn_mfma_f32_16x16x32_bf16(af[mb], bf[nb], acc[mb][nb], 0, 0, 0);
        }

        if (layer < 4) {
            #pragma unroll
            for (int mb = 0; mb < 4; ++mb) {
                #pragma unroll
                for (int nb = 0; nb < 4; ++nb) {
                    f32x4 a = acc[mb][nb];
                    uint2 pw;
                    pw.x = packbf2(fmaxf(a[0], 0.f), fmaxf(a[1], 0.f));
                    pw.y = packbf2(fmaxf(a[2], 0.f), fmaxf(a[3], 0.f));
                    *(uint2*)&B[(nb*16 + c)*BROW + mb*16 + g*4] = pw;
                }
            }
        }
    }

    // epilogue: ReLU + max over neighbors; write raw-view array
    const int cc = q >> 7;
    const int pbase = (q & 127) << 6;
    #pragma unroll
    for (int mb = 0; mb < 4; ++mb) {
        float v[4];
        #pragma unroll
        for (int r = 0; r < 4; ++r)
            v[r] = fmaxf(fmaxf(fmaxf(acc[mb][0][r], acc[mb][1][r]),
                               fmaxf(acc[mb][2][r], acc[mb][3][r])), 0.f);
        #pragma unroll
        for (int mask = 1; mask <= 8; mask <<= 1)
            #pragma unroll
            for (int r = 0; r < 4; ++r)
                v[r] = fmaxf(v[r], __shfl_xor(v[r], mask));
        if (c == 0) {
            #pragma unroll
            for (int r = 0; r < 4; ++r) {
                const int f = mb*16 + g*4 + r;
                xb3v[(size_t)(pbase + f) * 64 + cc] = f2bf(v[r]);
            }
        }
    }

    // ---- conv1-stats side-job (blocks 0..63; block-uniform branch) ----
    if (blockIdx.x < 64) {
        __syncthreads();                          // all waves done with Blds
        float* sps  = (float*)&Blds[0][0];        // overlay: ps[4][32]
        float* spss = sps + 128;                  //          pss[4][32]
        const int tid = threadIdx.x;
        const int bx = blockIdx.x & 31, by = blockIdx.x >> 5;
        const int p  = bx * 256 + tid;
        const int o0 = by * 32;
        const float* fdn = ws + OFF_FEATDN;       // flat raw-view
        const float* wt1 = ws + OFF_WT1;
        float* s1 = ws + OFF_STATS;
        float xv0 = fdn[p], xv1 = fdn[8192 + p], xv2 = fdn[16384 + p], xv3 = fdn[24576 + p];
        float accc[32];
        #pragma unroll
        for (int u = 0; u < 32; ++u) accc[u] = c1b[o0 + u];
        #pragma unroll
        for (int u = 0; u < 32; ++u) accc[u] = fmaf(xv0, wt1[0*64 + o0 + u], accc[u]);
        #pragma unroll
        for (int u = 0; u < 32; ++u) accc[u] = fmaf(xv1, wt1[1*64 + o0 + u], accc[u]);
        #pragma unroll
        for (int u = 0; u < 32; ++u) accc[u] = fmaf(xv2, wt1[2*64 + o0 + u], accc[u]);
        #pragma unroll
        for (int u = 0; u < 32; ++u) accc[u] = fmaf(xv3, wt1[3*64 + o0 + u], accc[u]);
        #pragma unroll
        for (int u = 0; u < 32; ++u) {
            float s = accc[u], ss = accc[u] * accc[u];
            for (int j = 32; j > 0; j >>= 1) { s += __shfl_xor(s, j); ss += __shfl_xor(ss, j); }
            if (lane == 0) { sps[wid*32 + u] = s; spss[wid*32 + u] = ss; }
        }
        __syncthreads();
        if (tid < 32) {
            float S  = sps[tid] + sps[32 + tid] + sps[64 + tid] + sps[96 + tid];
            float SS = spss[tid] + spss[32 + tid] + spss[64 + tid] + spss[96 + tid];
            atomicAdd(&s1[o0 + tid], S);
            atomicAdd(&s1[64 + o0 + tid], SS);
        }
    }
}

// XCD-aware bijective block swizzle (T1). nwg % 8 == 0 required (64/128/512 ok).
__device__ __forceinline__ void xcd_tile(int nwg, int MB, int& nb, int& mb) {
    const int bid = blockIdx.x;
    const int bidp = (bid & 7) * (nwg >> 3) + (bid >> 3);
    mb = bidp % MB;
    nb = bidp / MB;
}

// ---------------- conv2fd: conv2 MFMA with conv1+BN1+ReLU+bf16 built on the fly ----------------
__global__ __launch_bounds__(256) void conv2fd_kernel(
    const unsigned short* __restrict__ A,
    const float* __restrict__ c1b,
    const float* __restrict__ stp, const float* __restrict__ gam, const float* __restrict__ bet,
    const float* __restrict__ bias, float* __restrict__ yout, float* __restrict__ stout,
    const float* __restrict__ ws)
{
    __shared__ float sc[64], sh[64], swt[256], sb[64];
    const int tid = threadIdx.x;
    if (tid < 64) {
        float mu  = stp[tid] * (1.f / 8192.f);
        float var = stp[64 + tid] * (1.f / 8192.f) - mu * mu;
        float s = gam[tid] / sqrtf(var + 1e-5f);
        sc[tid] = s; sh[tid] = bet[tid] - mu * s;
        sb[tid] = c1b[tid];
    }
    if (tid < 256) swt[tid] = ws[OFF_WT1 + tid];
    __syncthreads();

    const float* fdn = ws + OFF_FEATDN;
    const int lane = tid & 63;
    const int w = tid >> 6;
    int nb, mb;
    xcd_tile(64, 2, nb, mb);
    const int n0 = nb * 256 + w * 64;
    const int m0 = mb * 64;
    const int c = lane & 15, g = lane >> 4;
    const int K = 64, M = 128;

    f32x4 acc[4][4];
    #pragma unroll
    for (int mt = 0; mt < 4; ++mt)
        #pragma unroll
        for (int nt = 0; nt < 4; ++nt)
            acc[mt][nt] = (f32x4){0.f, 0.f, 0.f, 0.f};

    for (int k0 = 0; k0 < K; k0 += 32) {
        bf16x8 af[4], bf[4];
        #pragma unroll
        for (int mt = 0; mt < 4; ++mt)
            af[mt] = *(const bf16x8*)(A + (size_t)(m0 + mt*16 + c) * K + k0 + g*8);
        const int ch0 = k0 + g*8;
        #pragma unroll
        for (int nt = 0; nt < 4; ++nt) {
            const int pt = n0 + nt*16 + c;
            const float fd0 = fdn[pt];
            const float fd1 = fdn[8192 + pt];
            const float fd2 = fdn[16384 + pt];
            const float fd3 = fdn[24576 + pt];
            bf16x8 r;
            #pragma unroll
            for (int j = 0; j < 8; ++j) {
                const int ch = ch0 + j;
                float v = fmaf(fd3, swt[192 + ch],
                          fmaf(fd2, swt[128 + ch],
                          fmaf(fd1, swt[64 + ch],
                          fmaf(fd0, swt[ch], sb[ch]))));
                r[j] = (__bf16)fmaxf(fmaf(v, sc[ch], sh[ch]), 0.f);
            }
            bf[nt] = r;
        }
        #pragma unroll
        for (int mt = 0; mt < 4; ++mt)
            #pragma unroll
            for (int nt = 0; nt < 4; ++nt)
                acc[mt][nt] = __builtin_amdgcn_mfma_f32_16x16x32_bf16(af[mt], bf[nt], acc[mt][nt], 0, 0, 0);
    }

    #pragma unroll
    for (int mt = 0; mt < 4; ++mt) {
        float s[4], ss[4];
        #pragma unroll
        for (int r = 0; r < 4; ++r) {
            const int o = m0 + mt*16 + g*4 + r;
            const float bv = bias[o];
            float sum = 0.f, sq = 0.f;
            #pragma unroll
            for (int nt = 0; nt < 4; ++nt) {
                float v = acc[mt][nt][r] + bv;
                yout[(size_t)o * NPTS + n0 + nt*16 + c] = v;
                sum += v; sq += v * v;
            }
            s[r] = sum; ss[r] = sq;
        }
        #pragma unroll
        for (int mask = 1; mask <= 8; mask <<= 1)
            #pragma unroll
            for (int r = 0; r < 4; ++r) {
                s[r]  += __shfl_xor(s[r],  mask);
                ss[r] += __shfl_xor(ss[r], mask);
            }
        if (c == 0) {
            #pragma unroll
            for (int r = 0; r < 4; ++r) {
                const int o = m0 + mt*16 + g*4 + r;
                atomicAdd(&stout[o], s[r]);
                atomicAdd(&stout[M + o], ss[r]);
            }
        }
    }
}

// ---------------- convbn: MFMA conv with previous-layer BN+ReLU+bf16 applied on the fly ----------------
__global__ __launch_bounds__(256) void convbn_kernel(
    const unsigned short* __restrict__ A,
    const unsigned short* __restrict__ Bdir, int Kdir,
    const float* __restrict__ yprev,
    const float* __restrict__ stp, const float* __restrict__ gam, const float* __restrict__ bet,
    const float* __restrict__ bias, int K, int M,
    float* __restrict__ yout, float* __restrict__ stout)
{
    __shared__ float sc[256], sh[256];
    const int tid = threadIdx.x;
    const int Cp = K - Kdir;
    for (int cc = tid; cc < Cp; cc += 256) {
        float mu  = stp[cc] * (1.f / 8192.f);
        float var = stp[Cp + cc] * (1.f / 8192.f) - mu * mu;
        float s = gam[cc] / sqrtf(var + 1e-5f);
        sc[cc] = s; sh[cc] = bet[cc] - mu * s;
    }
    __syncthreads();

    const int lane = tid & 63;
    const int w = tid >> 6;
    int nb, mb;
    xcd_tile(gridDim.x, M >> 6, nb, mb);
    const int n0 = nb * 256 + w * 64;
    const int m0 = mb * 64;
    const int c = lane & 15, g = lane >> 4;

    f32x4 acc[4][4];
    #pragma unroll
    for (int mt = 0; mt < 4; ++mt)
        #pragma unroll
        for (int nt = 0; nt < 4; ++nt)
            acc[mt][nt] = (f32x4){0.f, 0.f, 0.f, 0.f};

    for (int k0 = 0; k0 < K; k0 += 32) {
        bf16x8 af[4], bf[4];
        #pragma unroll
        for (int mt = 0; mt < 4; ++mt)
            af[mt] = *(const bf16x8*)(A + (size_t)(m0 + mt*16 + c) * K + k0 + g*8);
        if (k0 + 32 <= Kdir) {
            #pragma unroll
            for (int nt = 0; nt < 4; ++nt)
                bf[nt] = *(const bf16x8*)(Bdir + (size_t)(n0 + nt*16 + c) * Kdir + k0 + g*8);
        } else {
            const int ch0 = k0 - Kdir + g*8;
            #pragma unroll
            for (int nt = 0; nt < 4; ++nt) {
                const int pt = n0 + nt*16 + c;
                bf16x8 r;
                #pragma unroll
                for (int j = 0; j < 8; ++j) {
                    float vv = fmaxf(fmaf(yprev[(size_t)(ch0 + j) * NPTS + pt],
                                          sc[ch0 + j], sh[ch0 + j]), 0.f);
                    r[j] = (__bf16)vv;
                }
                bf[nt] = r;
            }
        }
        #pragma unroll
        for (int mt = 0; mt < 4; ++mt)
            #pragma unroll
            for (int nt = 0; nt < 4; ++nt)
                acc[mt][nt] = __builtin_amdgcn_mfma_f32_16x16x32_bf16(af[mt], bf[nt], acc[mt][nt], 0, 0, 0);
    }

    #pragma unroll
    for (int mt = 0; mt < 4; ++mt) {
        float s[4], ss[4];
        #pragma unroll
        for (int r = 0; r < 4; ++r) {
            const int o = m0 + mt*16 + g*4 + r;
            const float bv = bias[o];
            float sum = 0.f, sq = 0.f;
            #pragma unroll
            for (int nt = 0; nt < 4; ++nt) {
                float v = acc[mt][nt][r] + bv;
                yout[(size_t)o * NPTS + n0 + nt*16 + c] = v;
                sum += v; sq += v * v;
            }
            s[r] = sum; ss[r] = sq;
        }
        #pragma unroll
        for (int mask = 1; mask <= 8; mask <<= 1)
            #pragma unroll
            for (int r = 0; r < 4; ++r) {
                s[r]  += __shfl_xor(s[r],  mask);
                ss[r] += __shfl_xor(ss[r], mask);
            }
        if (c == 0) {
            #pragma unroll
            for (int r = 0; r < 4; ++r) {
                const int o = m0 + mt*16 + g*4 + r;
                atomicAdd(&stout[o], s[r]);
                atomicAdd(&stout[M + o], ss[r]);
            }
        }
    }
}

// ---------------- final BN + ReLU (in place on d_out), float4-vectorized ----------------
__global__ __launch_bounds__(256) void bnrelu_kernel(
    const float4* y, const float* __restrict__ st,
    const float* __restrict__ g, const float* __restrict__ b,
    float4* out, int C)
{
    int idx = blockIdx.x * 256 + threadIdx.x;   // float4 index
    int c = idx >> 11;   // N/4 = 2048 float4 per channel row
    float mu  = st[c] * (1.f / 8192.f);
    float var = st[C + c] * (1.f / 8192.f) - mu * mu;
    float scale = g[c] / sqrtf(var + 1e-5f);
    float sh = b[c] - mu * scale;
    float4 v = y[idx];
    v.x = fmaxf(fmaf(v.x, scale, sh), 0.f);
    v.y = fmaxf(fmaf(v.y, scale, sh), 0.f);
    v.z = fmaxf(fmaf(v.z, scale, sh), 0.f);
    v.w = fmaxf(fmaf(v.w, scale, sh), 0.f);
    out[idx] = v;
}

extern "C" void kernel_launch(void* const* d_in, const int* in_sizes, int n_in,
                              void* d_out, int out_size, void* d_ws, size_t ws_size,
                              hipStream_t stream) {
    const float* points = (const float*)d_in[0];
    const float* gw0 = (const float*)d_in[1];
    const float* gw1 = (const float*)d_in[2];
    const float* gw2 = (const float*)d_in[3];
    const float* gw3 = (const float*)d_in[4];
    const float* gw4 = (const float*)d_in[5];
    const float* c1w = (const float*)d_in[6];  const float* c1b = (const float*)d_in[7];
    const float* bn1g = (const float*)d_in[8]; const float* bn1b = (const float*)d_in[9];
    const float* c2w = (const float*)d_in[10]; const float* c2b = (const float*)d_in[11];
    const float* bn2g = (const float*)d_in[12];const float* bn2b = (const float*)d_in[13];
    const float* c3w = (const float*)d_in[14]; const float* c3b = (const float*)d_in[15];
    const float* bn3g = (const float*)d_in[16];const float* bn3b = (const float*)d_in[17];
    const float* c4w = (const float*)d_in[18]; const float* c4b = (const float*)d_in[19];
    const float* bn4g = (const float*)d_in[20];const float* bn4b = (const float*)d_in[21];

    float* ws = (float*)d_ws;
    float* p4f    = ws + OFF_P4;
    float* featup = ws + OFF_FEATUP;
    float* y2 = ws + OFF_Y2; float* y3 = ws + OFF_Y3;
    float* s1 = ws + OFF_STATS + 0;
    float* s2 = ws + OFF_STATS + 128;
    float* s3 = ws + OFF_STATS + 384;
    float* s4 = ws + OFF_STATS + 896;
    const unsigned short* gwt = (const unsigned short*)(ws + OFF_GWT);
    const unsigned short* bw2 = (const unsigned short*)(ws + OFF_BW2);
    const unsigned short* bw3 = (const unsigned short*)(ws + OFF_BW3);
    const unsigned short* bw4 = (const unsigned short*)(ws + OFF_BW4);
    unsigned short* xb3v = (unsigned short*)(ws + OFF_XB3V);
    float* outp = (float*)d_out;

    prepwt_kernel<<<256, 256, 0, stream>>>(points, c1w, c2w, c3w, c4w,
                                           gw0, gw1, gw2, gw3, gw4, ws);
    // shell-compact points for the banded KNN
    scatter_kernel<<<32, 256, 0, stream>>>(ws);

    // knn (radial-shell pruned) + feat_up + feat_down
    knn_feat_kernel<<<1024, 512, 0, stream>>>((const float4*)p4f,
                                              (const float4*)(ws + OFF_P4S),
                                              (const unsigned*)(ws + OFF_IDXS),
                                              (float4*)featup, ws);
    // mlp + conv1-stats side-job (blocks 0..63)
    mlp_kernel<<<2048, 256, 0, stream>>>((const float4*)featup, gwt, xb3v, c1b, ws);

    // conv2 with conv1+BN1 on the fly (XCD-swizzled): -> y2 + s2
    conv2fd_kernel<<<64, 256, 0, stream>>>(bw2, c1b, s1, bn1g, bn1b,
                                           c2b, y2, s2, ws);
    // conv3 (XCD-swizzled): cols 0..63 from xb3v, cols 64..191 = BN2(y2)
    convbn_kernel<<<128, 256, 0, stream>>>(bw3, xb3v, 64, y2, s2, bn2g, bn2b,
                                           c3b, 192, 256, y3, s3);
    // conv4 (XCD-swizzled) with BN3 on the fly -> d_out channel-major (pre-BN4) + s4
    convbn_kernel<<<512, 256, 0, stream>>>(bw4, nullptr, 0, y3, s3, bn3g, bn3b,
                                           c4b, 256, 1024, outp, s4);
    // final BN4 + ReLU in place
    bnrelu_kernel<<<8192, 256, 0, stream>>>((const float4*)outp, s4, bn4g, bn4b, (float4*)outp, 1024);
}

// Round 17
// 331.089 us; speedup vs baseline: 1.0036x; 1.0036x over previous
//
#include <hip/hip_runtime.h>
#include <hip/hip_bf16.h>

#define NPTS 8192
#define KNN 64
#define EPSF 1e-7f
#define BINW 0.075f
#define INVW (1.0f/0.075f)
#define SCAP 1024                  // per-shell capacity (fixed stride); overflow handled exactly

// ---------------- workspace layout (float offsets) ----------------
#define OFF_P4      0              // packed (x,y,z,rr) float4 per point: 4*N
#define OFF_STATS   32768          // s1:+0(128) s2:+128(256) s3:+384(512) s4:+896(2048) = 2944
#define OFF_C       35712          // 64 shell cursors + 1 ovf cursor (u32; zeroed via hipMemsetAsync)
#define OFF_PART    36012          // 32 blocks x 2 u64 = 128 floats
#define OFF_FEATDN  36864          // N*4 -> 69632 (raw-view source for conv1-on-the-fly)
#define OFF_WT1     69632          // 4*64 fp32 transposed -> 69888
#define OFF_GWT     69888          // MLP bf16 weights -> 79104
#define OFF_BW2     79104          // -> 83200
#define OFF_BW3     83200          // -> 107776
#define OFF_BW4     107776         // -> 238848
#define OFF_XB3V    238848         // bf16 raw-view emb_up [8192][64] -> 500992
#define OFF_P4S     501248         // shell segments float4[64*1024] -> 763392
#define OFF_IDXS    763392         // u32[64*1024] -> 828928
#define OFF_OVF4    828928         // overflow float4[8192] -> 861696
#define OFF_OVFI    861696         // overflow u32[8192] -> 869888
#define OFF_Y2      2860288        // 128*N fp32 channel-major -> 3908864
#define OFF_Y3      3908864        // 256*N fp32 channel-major -> 6006016
#define OFF_FEATUP  6006016        // N*K*4 fp32 -> 8103168

typedef __bf16 bf16x8 __attribute__((ext_vector_type(8)));
typedef float  f32x4  __attribute__((ext_vector_type(4)));

__device__ __forceinline__ unsigned f2u(float f) {
    unsigned u = __float_as_uint(f);
    return ((int)u >= 0) ? (u | 0x80000000u) : ~u;
}
__device__ __forceinline__ float key_to_f(unsigned long long k) {
    unsigned v = (unsigned)(k >> 32);
    unsigned ob = (v & 0x80000000u) ? (v ^ 0x80000000u) : ~v;
    return __uint_as_float(ob);
}
__device__ __forceinline__ unsigned short f2bf(float x) {
    union { __bf16 h; unsigned short s; } u;
    u.h = (__bf16)x;
    return u.s;
}
__device__ __forceinline__ unsigned packbf2(float lo, float hi) {
    return (unsigned)f2bf(lo) | ((unsigned)f2bf(hi) << 16);
}
__device__ __forceinline__ unsigned long long u64min(unsigned long long a, unsigned long long b){ return a < b ? a : b; }
__device__ __forceinline__ unsigned long long u64max(unsigned long long a, unsigned long long b){ return a < b ? b : a; }

__device__ __forceinline__ unsigned long long sort_merge(
    unsigned long long key, unsigned long long cur, int lane)
{
    #pragma unroll
    for (int k = 2; k <= 64; k <<= 1) {
        #pragma unroll
        for (int j = k >> 1; j > 0; j >>= 1) {
            unsigned long long o = __shfl_xor(key, j);
            bool up = ((lane & k) == 0);
            bool lower = ((lane & j) == 0);
            key = (lower == up) ? u64min(key, o) : u64max(key, o);
        }
    }
    unsigned long long rev = __shfl(key, 63 - lane);
    unsigned long long m = u64min(cur, rev);
    #pragma unroll
    for (int j = 32; j > 0; j >>= 1) {
        unsigned long long o = __shfl_xor(m, j);
        m = ((lane & j) == 0) ? u64min(m, o) : u64max(m, o);
    }
    return m;
}

// ---------------- prep A + weight prep + DIRECT shell scatter ----------------
// Shell cursors (OFF_C) are zeroed by hipMemsetAsync before this kernel.
__global__ __launch_bounds__(256) void prepwt_kernel(
    const float* __restrict__ points,
    const float* __restrict__ c1w, const float* __restrict__ c2w,
    const float* __restrict__ c3w, const float* __restrict__ c4w,
    const float* __restrict__ gw0, const float* __restrict__ gw1,
    const float* __restrict__ gw2, const float* __restrict__ gw3,
    const float* __restrict__ gw4,
    float* __restrict__ ws)
{
    const int t = blockIdx.x * 256 + threadIdx.x;
    const int T = 256 * 256;
    for (int m = t; m < 2944; m += T) ws[OFF_STATS + m] = 0.f;
    for (int m = t; m < 64*4; m += T) { int o = m >> 2, c = m & 3; ws[OFF_WT1 + c*64 + o] = c1w[m]; }

    unsigned short* bw2 = (unsigned short*)(ws + OFF_BW2);
    for (int m = t; m < 128*64; m += T)   bw2[m] = f2bf(c2w[m]);
    unsigned short* bw3 = (unsigned short*)(ws + OFF_BW3);
    for (int m = t; m < 256*192; m += T)  bw3[m] = f2bf(c3w[m]);
    unsigned short* bw4 = (unsigned short*)(ws + OFF_BW4);
    for (int m = t; m < 1024*256; m += T) bw4[m] = f2bf(c4w[m]);

    unsigned short* gwt = (unsigned short*)(ws + OFF_GWT);
    for (int m = t; m < 2048; m += T) {          // gw0T padded [64][32]
        int o = m >> 5, i = m & 31;
        gwt[m] = (i < 4) ? f2bf(gw0[i*64 + o]) : (unsigned short)0;
    }
    const float* gsrc[4] = {gw1, gw2, gw3, gw4};
    for (int l = 0; l < 4; ++l) {
        const float* g = gsrc[l];
        unsigned short* dst = gwt + 2048 + l*4096;
        for (int m = t; m < 4096; m += T) { int o = m >> 6, i = m & 63; dst[m] = f2bf(g[i*64 + o]); }
    }

    // ---- prep_a part (blocks 0..31 only): p4 + direct shell scatter + part-reduce ----
    if (blockIdx.x < 32) {
        const int n = blockIdx.x * 256 + threadIdx.x;
        float x = points[3*n+0], y = points[3*n+1], z = points[3*n+2];
        float rr = x*x + y*y + z*z;
        float4 v4 = make_float4(x, y, z, rr);
        ((float4*)(ws + OFF_P4))[n] = v4;
        float vn = sqrtf(rr);
        int bin = (int)(vn * INVW); if (bin > 63) bin = 63;
        unsigned* C = (unsigned*)(ws + OFF_C);
        unsigned pos = atomicAdd(&C[bin], 1u);
        if (pos < SCAP) {
            ((float4*)(ws + OFF_P4S))[bin * SCAP + pos] = v4;
            ((unsigned*)(ws + OFF_IDXS))[bin * SCAP + pos] = (unsigned)n;
        } else {
            unsigned op = atomicAdd(&C[64], 1u);
            ((float4*)(ws + OFF_OVF4))[op] = v4;
            ((unsigned*)(ws + OFF_OVFI))[op] = (unsigned)n;
        }
        unsigned b = __float_as_uint(vn);
        unsigned long long mxk = ((unsigned long long)b << 32) | (unsigned long long)(0xFFFFFFFFu - (unsigned)n);
        unsigned long long mnk = ((unsigned long long)b << 32) | (unsigned long long)(unsigned)n;
        for (int j = 32; j > 0; j >>= 1) {
            mxk = u64max(mxk, __shfl_xor(mxk, j));
            mnk = u64min(mnk, __shfl_xor(mnk, j));
        }
        __shared__ unsigned long long smx[4], smn[4];
        int wid = threadIdx.x >> 6;
        if ((threadIdx.x & 63) == 0) { smx[wid] = mxk; smn[wid] = mnk; }
        __syncthreads();
        if (threadIdx.x == 0) {
            unsigned long long MX = 0ull, MN = ~0ull;
            for (int i = 0; i < 4; ++i) { MX = u64max(MX, smx[i]); MN = u64min(MN, smn[i]); }
            unsigned long long* parts = (unsigned long long*)(ws + OFF_PART);
            parts[2*blockIdx.x + 0] = MX;
            parts[2*blockIdx.x + 1] = MN;
        }
    }
}

// ---------------- KNN via radial-shell pruning + features + feat_down ----------------
// 1 query/wave, 8 waves/block, LDS 8 KB. Shell b occupies [b*SCAP, b*SCAP+cnt[b]);
// overflow segment (normally empty) scanned unconditionally -> exact for any data.
// Keys carry ORIGINAL indices -> selection bit-identical to full scan.
__global__ __launch_bounds__(512) void knn_feat_kernel(
    const float4* __restrict__ p4, const float4* __restrict__ p4s,
    const unsigned* __restrict__ idxs,
    const float4* __restrict__ ovf4, const unsigned* __restrict__ ovfi,
    float4* __restrict__ feat_up, float* __restrict__ ws)
{
    __shared__ unsigned long long queue[8][128];
    const int lane = threadIdx.x & 63;
    const int wid  = threadIdx.x >> 6;
    const int q = blockIdx.x * 8 + wid;

    const unsigned* Cc = (const unsigned*)(ws + OFF_C);
    const int cnt_l = (int)Cc[lane];               // lane b holds raw cursor of shell b
    const int ocnt = (int)Cc[64];                  // overflow count (normally 0)

    const float4 qa = p4[q];
    const float qn = sqrtf(qa.w);
    unsigned long long cur = ~0ull;
    float ke = __builtin_inff();
    int qc = 0;
    unsigned long long* Q = queue[wid];

#define SCANR(PARR, IARR, S_, E_) { \
    for (int off = (S_); off < (E_); off += 64) { \
        const int jj = off + lane; \
        float e0 = __builtin_inff(); \
        if (jj < (E_)) { \
            float4 cd = (PARR)[jj]; \
            float dot = fmaf(qa.x, cd.x, fmaf(qa.y, cd.y, qa.z * cd.z)); \
            e0 = fmaf(-2.f, dot, cd.w); \
        } \
        bool p = e0 < ke; \
        unsigned long long m = __ballot(p); \
        if (m) { \
            int prefix = __builtin_amdgcn_mbcnt_hi((unsigned)(m >> 32), \
                          __builtin_amdgcn_mbcnt_lo((unsigned)m, 0)); \
            if (p) Q[qc + prefix] = ((unsigned long long)f2u(e0) << 32) \
                                  | (unsigned long long)(IARR)[jj]; \
            qc += __popcll(m); \
            if (qc >= 64) { \
                qc -= 64; \
                cur = sort_merge(Q[qc + lane], cur, lane); \
                ke = key_to_f(__shfl(cur, 63)); \
            } \
        } \
    } }

    // overflow segment first (normally empty; exactness for pathological data)
    SCANR(ovf4, ovfi, 0, ocnt);

#define SCANB(BB) { \
    const int s_ = (BB) << 10; \
    int cb_ = __shfl(cnt_l, (BB)); if (cb_ > SCAP) cb_ = SCAP; \
    const int e_ = s_ + cb_; \
    SCANR(p4s, idxs, s_, e_) }

    int b0 = (int)(qn * INVW); if (b0 > 63) b0 = 63;
    int br = b0, bl = b0 - 1;
    bool rOK = true, lOK = (bl >= 0);
    while (rOK || lOK) {
        if (rOK) {
            if (br >= 64) rOK = false;
            else {
                bool go = true;
                if (br > b0) {
                    float d = br * BINW - qn;                    // lower bound on |p| gap
                    if (d > 0.f && d*d > fmaf(ke + qa.w, 1.0001f, 1e-4f)) go = false;
                }
                if (!go) rOK = false;
                else { SCANB(br); ++br; }
            }
        }
        if (lOK) {
            if (bl < 0) lOK = false;
            else {
                float d = qn - (bl + 1) * BINW;                  // upper bound of shell bl
                bool go = !(d > 0.f && d*d > fmaf(ke + qa.w, 1.0001f, 1e-4f));
                if (!go) lOK = false;
                else { SCANB(bl); --bl; }
            }
        }
    }
#undef SCANB
#undef SCANR
    cur = sort_merge((lane < qc) ? Q[lane] : ~0ull, cur, lane);

    // feature epilogue (feat_up) — identical to full-scan version
    int nidx = (int)(unsigned)(cur & 0xFFFFFFFFu);
    float4 np = p4[nidx];
    float ox = __shfl(np.x, 0), oy = __shfl(np.y, 0), oz = __shfl(np.z, 0);
    float pcx = np.x - ox, pcy = np.y - oy, pcz = np.z - oz;
    float vn = sqrtf(pcx*pcx + pcy*pcy + pcz*pcz);

    unsigned long long ak = ((unsigned long long)__float_as_uint(vn) << 32)
                          | (unsigned long long)(unsigned)(63 - lane);
    for (int s = 32; s > 0; s >>= 1) ak = u64max(ak, __shfl_xor(ak, s));
    int id1 = 63 - (int)(unsigned)(ak & 0xFFFFFFFFu);

    float a1x = __shfl(pcx, id1), a1y = __shfl(pcy, id1), a1z = __shfl(pcz, id1);
    float n1 = sqrtf(a1x*a1x + a1y*a1y + a1z*a1z) + EPSF;
    a1x /= n1; a1y /= n1; a1z /= n1;

    float sx = pcx, sy = pcy, sz = pcz;
    for (int s = 32; s > 0; s >>= 1) {
        sx += __shfl_xor(sx, s); sy += __shfl_xor(sy, s); sz += __shfl_xor(sz, s);
    }
    float a2x = sx * (1.f/64.f), a2y = sy * (1.f/64.f), a2z = sz * (1.f/64.f);
    float n2 = sqrtf(a2x*a2x + a2y*a2y + a2z*a2z) + EPSF;
    a2x /= n2; a2y /= n2; a2z /= n2;

    float a3x = a1x + 1.5f*a2x, a3y = a1y + 1.5f*a2y, a3z = a1z + 1.5f*a2z;
    float n3 = sqrtf(a3x*a3x + a3y*a3y + a3z*a3z) + EPSF;
    a3x /= n3; a3y /= n3; a3z /= n3;

    float den = vn + EPSF;
    float f1 = (pcx*a1x + pcy*a1y + pcz*a1z) / den;
    float f2 = (pcx*a2x + pcy*a2y + pcz*a2z) / den;
    float f3 = (pcx*a3x + pcy*a3y + pcz*a3z) / den;
    feat_up[q*64 + lane] = make_float4(f1, f2, f3, vn);

    // feat_down (prep_c folded): per-wave parts-reduce in registers, lane 0 writes.
    {
        const unsigned long long* parts = (const unsigned long long*)(ws + OFF_PART);
        unsigned long long mxk = (lane < 32) ? parts[2*lane + 0] : 0ull;
        unsigned long long mnk = (lane < 32) ? parts[2*lane + 1] : ~0ull;
        for (int s = 32; s > 0; s >>= 1) {
            mxk = u64max(mxk, __shfl_xor(mxk, s));
            mnk = u64min(mnk, __shfl_xor(mnk, s));
        }
        if (lane == 0) {
            int i1 = (int)(0xFFFFFFFFu - (unsigned)(mxk & 0xFFFFFFFFu));
            int i2 = (int)(unsigned)(mnk & 0xFFFFFFFFu);
            float4 p1 = p4[i1];
            float4 p2 = p4[i2];
            float w1 = sqrtf(p1.x*p1.x + p1.y*p1.y + p1.z*p1.z) + EPSF;
            float b1x = p1.x/w1, b1y = p1.y/w1, b1z = p1.z/w1;
            float w2 = sqrtf(p2.x*p2.x + p2.y*p2.y + p2.z*p2.z) + EPSF;
            float b2x = p2.x/w2, b2y = p2.y/w2, b2z = p2.z/w2;
            float b3x = b1x + 1.5f*b2x, b3y = b1y + 1.5f*b2y, b3z = b1z + 1.5f*b2z;
            float w3 = sqrtf(b3x*b3x + b3y*b3y + b3z*b3z) + EPSF;
            b3x /= w3; b3y /= w3; b3z /= w3;
            float vq = sqrtf(qa.w);
            float dq = vq + EPSF;
            float g1 = (qa.x*b1x + qa.y*b1y + qa.z*b1z) / dq;
            float g2 = (qa.x*b2x + qa.y*b2y + qa.z*b2z) / dq;
            float g3 = (qa.x*b3x + qa.y*b3y + qa.z*b3z) / dq;
            ((float4*)(ws + OFF_FEATDN))[q] = make_float4(g1, g2, g3, vq);
        }
    }
}

// ---------------- 5-layer MLP via bf16 MFMA + max over K + conv1-STATS side-job ----------------
#define BROW 72
__global__ __launch_bounds__(256) void mlp_kernel(
    const float4* __restrict__ feat_up,
    const unsigned short* __restrict__ gwt,
    unsigned short* __restrict__ xb3v,
    const float* __restrict__ c1b,
    float* __restrict__ ws)
{
    __shared__ __align__(16) unsigned short Blds[4][64 * BROW];
    const int lane = threadIdx.x & 63;
    const int wid  = threadIdx.x >> 6;
    const int q = blockIdx.x * 4 + wid;
    const int c = lane & 15, g = lane >> 4;
    unsigned short* B = Blds[wid];

    {
        float4 f = feat_up[q*64 + lane];
        uint2 p0;
        p0.x = packbf2(f.x, f.y);
        p0.y = packbf2(f.z, f.w);
        *(uint2*)&B[lane*BROW] = p0;
        *(uint2*)&B[lane*BROW + 4] = make_uint2(0, 0);
        uint4 z4 = make_uint4(0, 0, 0, 0);
        *(uint4*)&B[lane*BROW + 8]  = z4;
        *(uint4*)&B[lane*BROW + 16] = z4;
        *(uint4*)&B[lane*BROW + 24] = z4;
    }

    const unsigned short* Wl[5] = {gwt, gwt + 2048, gwt + 6144, gwt + 10240, gwt + 14336};
    f32x4 acc[4][4];

    for (int layer = 0; layer < 5; ++layer) {
        const int wstride = (layer == 0) ? 32 : 64;
        const int nks = (layer == 0) ? 1 : 2;
        #pragma unroll
        for (int mb = 0; mb < 4; ++mb)
            #pragma unroll
            for (int nb = 0; nb < 4; ++nb)
                acc[mb][nb] = (f32x4){0.f, 0.f, 0.f, 0.f};

        for (int ks = 0; ks < nks; ++ks) {
            bf16x8 af[4], bf[4];
            #pragma unroll
            for (int mb = 0; mb < 4; ++mb)
                af[mb] = *(const bf16x8*)(Wl[layer] + (mb*16 + c)*wstride + ks*32 + g*8);
            #pragma unroll
            for (int nb = 0; nb < 4; ++nb)
                bf[nb] = *(const bf16x8*)&B[(nb*16 + c)*BROW + ks*32 + g*8];
            #pragma unroll
            for (int mb = 0; mb < 4; ++mb)
                #pragma unroll
                for (int nb = 0; nb < 4; ++nb)
                    acc[mb][nb] = __builtin_amdgcn_mfma_f32_16x16x32_bf16(af[mb], bf[nb], acc[mb][nb], 0, 0, 0);
        }

        if (layer < 4) {
            #pragma unroll
            for (int mb = 0; mb < 4; ++mb) {
                #pragma unroll
                for (int nb = 0; nb < 4; ++nb) {
                    f32x4 a = acc[mb][nb];
                    uint2 pw;
                    pw.x = packbf2(fmaxf(a[0], 0.f), fmaxf(a[1], 0.f));
                    pw.y = packbf2(fmaxf(a[2], 0.f), fmaxf(a[3], 0.f));
                    *(uint2*)&B[(nb*16 + c)*BROW + mb*16 + g*4] = pw;
                }
            }
        }
    }

    // epilogue: ReLU + max over neighbors; write raw-view array
    const int cc = q >> 7;
    const int pbase = (q & 127) << 6;
    #pragma unroll
    for (int mb = 0; mb < 4; ++mb) {
        float v[4];
        #pragma unroll
        for (int r = 0; r < 4; ++r)
            v[r] = fmaxf(fmaxf(fmaxf(acc[mb][0][r], acc[mb][1][r]),
                               fmaxf(acc[mb][2][r], acc[mb][3][r])), 0.f);
        #pragma unroll
        for (int mask = 1; mask <= 8; mask <<= 1)
            #pragma unroll
            for (int r = 0; r < 4; ++r)
                v[r] = fmaxf(v[r], __shfl_xor(v[r], mask));
        if (c == 0) {
            #pragma unroll
            for (int r = 0; r < 4; ++r) {
                const int f = mb*16 + g*4 + r;
                xb3v[(size_t)(pbase + f) * 64 + cc] = f2bf(v[r]);
            }
        }
    }

    // ---- conv1-stats side-job (blocks 0..63; block-uniform branch) ----
    if (blockIdx.x < 64) {
        __syncthreads();                          // all waves done with Blds
        float* sps  = (float*)&Blds[0][0];        // overlay: ps[4][32]
        float* spss = sps + 128;                  //          pss[4][32]
        const int tid = threadIdx.x;
        const int bx = blockIdx.x & 31, by = blockIdx.x >> 5;
        const int p  = bx * 256 + tid;
        const int o0 = by * 32;
        const float* fdn = ws + OFF_FEATDN;       // flat raw-view
        const float* wt1 = ws + OFF_WT1;
        float* s1 = ws + OFF_STATS;
        float xv0 = fdn[p], xv1 = fdn[8192 + p], xv2 = fdn[16384 + p], xv3 = fdn[24576 + p];
        float accc[32];
        #pragma unroll
        for (int u = 0; u < 32; ++u) accc[u] = c1b[o0 + u];
        #pragma unroll
        for (int u = 0; u < 32; ++u) accc[u] = fmaf(xv0, wt1[0*64 + o0 + u], accc[u]);
        #pragma unroll
        for (int u = 0; u < 32; ++u) accc[u] = fmaf(xv1, wt1[1*64 + o0 + u], accc[u]);
        #pragma unroll
        for (int u = 0; u < 32; ++u) accc[u] = fmaf(xv2, wt1[2*64 + o0 + u], accc[u]);
        #pragma unroll
        for (int u = 0; u < 32; ++u) accc[u] = fmaf(xv3, wt1[3*64 + o0 + u], accc[u]);
        #pragma unroll
        for (int u = 0; u < 32; ++u) {
            float s = accc[u], ss = accc[u] * accc[u];
            for (int j = 32; j > 0; j >>= 1) { s += __shfl_xor(s, j); ss += __shfl_xor(ss, j); }
            if (lane == 0) { sps[wid*32 + u] = s; spss[wid*32 + u] = ss; }
        }
        __syncthreads();
        if (tid < 32) {
            float S  = sps[tid] + sps[32 + tid] + sps[64 + tid] + sps[96 + tid];
            float SS = spss[tid] + spss[32 + tid] + spss[64 + tid] + spss[96 + tid];
            atomicAdd(&s1[o0 + tid], S);
            atomicAdd(&s1[64 + o0 + tid], SS);
        }
    }
}

// XCD-aware bijective block swizzle (T1). nwg % 8 == 0 required (64/128/512 ok).
__device__ __forceinline__ void xcd_tile(int nwg, int MB, int& nb, int& mb) {
    const int bid = blockIdx.x;
    const int bidp = (bid & 7) * (nwg >> 3) + (bid >> 3);
    mb = bidp % MB;
    nb = bidp / MB;
}

// ---------------- conv2fd: conv2 MFMA with conv1+BN1+ReLU+bf16 built on the fly ----------------
__global__ __launch_bounds__(256) void conv2fd_kernel(
    const unsigned short* __restrict__ A,
    const float* __restrict__ c1b,
    const float* __restrict__ stp, const float* __restrict__ gam, const float* __restrict__ bet,
    const float* __restrict__ bias, float* __restrict__ yout, float* __restrict__ stout,
    const float* __restrict__ ws)
{
    __shared__ float sc[64], sh[64], swt[256], sb[64];
    const int tid = threadIdx.x;
    if (tid < 64) {
        float mu  = stp[tid] * (1.f / 8192.f);
        float var = stp[64 + tid] * (1.f / 8192.f) - mu * mu;
        float s = gam[tid] / sqrtf(var + 1e-5f);
        sc[tid] = s; sh[tid] = bet[tid] - mu * s;
        sb[tid] = c1b[tid];
    }
    if (tid < 256) swt[tid] = ws[OFF_WT1 + tid];
    __syncthreads();

    const float* fdn = ws + OFF_FEATDN;
    const int lane = tid & 63;
    const int w = tid >> 6;
    int nb, mb;
    xcd_tile(64, 2, nb, mb);
    const int n0 = nb * 256 + w * 64;
    const int m0 = mb * 64;
    const int c = lane & 15, g = lane >> 4;
    const int K = 64, M = 128;

    f32x4 acc[4][4];
    #pragma unroll
    for (int mt = 0; mt < 4; ++mt)
        #pragma unroll
        for (int nt = 0; nt < 4; ++nt)
            acc[mt][nt] = (f32x4){0.f, 0.f, 0.f, 0.f};

    for (int k0 = 0; k0 < K; k0 += 32) {
        bf16x8 af[4], bf[4];
        #pragma unroll
        for (int mt = 0; mt < 4; ++mt)
            af[mt] = *(const bf16x8*)(A + (size_t)(m0 + mt*16 + c) * K + k0 + g*8);
        const int ch0 = k0 + g*8;
        #pragma unroll
        for (int nt = 0; nt < 4; ++nt) {
            const int pt = n0 + nt*16 + c;
            const float fd0 = fdn[pt];
            const float fd1 = fdn[8192 + pt];
            const float fd2 = fdn[16384 + pt];
            const float fd3 = fdn[24576 + pt];
            bf16x8 r;
            #pragma unroll
            for (int j = 0; j < 8; ++j) {
                const int ch = ch0 + j;
                float v = fmaf(fd3, swt[192 + ch],
                          fmaf(fd2, swt[128 + ch],
                          fmaf(fd1, swt[64 + ch],
                          fmaf(fd0, swt[ch], sb[ch]))));
                r[j] = (__bf16)fmaxf(fmaf(v, sc[ch], sh[ch]), 0.f);
            }
            bf[nt] = r;
        }
        #pragma unroll
        for (int mt = 0; mt < 4; ++mt)
            #pragma unroll
            for (int nt = 0; nt < 4; ++nt)
                acc[mt][nt] = __builtin_amdgcn_mfma_f32_16x16x32_bf16(af[mt], bf[nt], acc[mt][nt], 0, 0, 0);
    }

    #pragma unroll
    for (int mt = 0; mt < 4; ++mt) {
        float s[4], ss[4];
        #pragma unroll
        for (int r = 0; r < 4; ++r) {
            const int o = m0 + mt*16 + g*4 + r;
            const float bv = bias[o];
            float sum = 0.f, sq = 0.f;
            #pragma unroll
            for (int nt = 0; nt < 4; ++nt) {
                float v = acc[mt][nt][r] + bv;
                yout[(size_t)o * NPTS + n0 + nt*16 + c] = v;
                sum += v; sq += v * v;
            }
            s[r] = sum; ss[r] = sq;
        }
        #pragma unroll
        for (int mask = 1; mask <= 8; mask <<= 1)
            #pragma unroll
            for (int r = 0; r < 4; ++r) {
                s[r]  += __shfl_xor(s[r],  mask);
                ss[r] += __shfl_xor(ss[r], mask);
            }
        if (c == 0) {
            #pragma unroll
            for (int r = 0; r < 4; ++r) {
                const int o = m0 + mt*16 + g*4 + r;
                atomicAdd(&stout[o], s[r]);
                atomicAdd(&stout[M + o], ss[r]);
            }
        }
    }
}

// ---------------- convbn: MFMA conv with previous-layer BN+ReLU+bf16 applied on the fly ----------------
__global__ __launch_bounds__(256) void convbn_kernel(
    const unsigned short* __restrict__ A,
    const unsigned short* __restrict__ Bdir, int Kdir,
    const float* __restrict__ yprev,
    const float* __restrict__ stp, const float* __restrict__ gam, const float* __restrict__ bet,
    const float* __restrict__ bias, int K, int M,
    float* __restrict__ yout, float* __restrict__ stout)
{
    __shared__ float sc[256], sh[256];
    const int tid = threadIdx.x;
    const int Cp = K - Kdir;
    for (int cc = tid; cc < Cp; cc += 256) {
        float mu  = stp[cc] * (1.f / 8192.f);
        float var = stp[Cp + cc] * (1.f / 8192.f) - mu * mu;
        float s = gam[cc] / sqrtf(var + 1e-5f);
        sc[cc] = s; sh[cc] = bet[cc] - mu * s;
    }
    __syncthreads();

    const int lane = tid & 63;
    const int w = tid >> 6;
    int nb, mb;
    xcd_tile(gridDim.x, M >> 6, nb, mb);
    const int n0 = nb * 256 + w * 64;
    const int m0 = mb * 64;
    const int c = lane & 15, g = lane >> 4;

    f32x4 acc[4][4];
    #pragma unroll
    for (int mt = 0; mt < 4; ++mt)
        #pragma unroll
        for (int nt = 0; nt < 4; ++nt)
            acc[mt][nt] = (f32x4){0.f, 0.f, 0.f, 0.f};

    for (int k0 = 0; k0 < K; k0 += 32) {
        bf16x8 af[4], bf[4];
        #pragma unroll
        for (int mt = 0; mt < 4; ++mt)
            af[mt] = *(const bf16x8*)(A + (size_t)(m0 + mt*16 + c) * K + k0 + g*8);
        if (k0 + 32 <= Kdir) {
            #pragma unroll
            for (int nt = 0; nt < 4; ++nt)
                bf[nt] = *(const bf16x8*)(Bdir + (size_t)(n0 + nt*16 + c) * Kdir + k0 + g*8);
        } else {
            const int ch0 = k0 - Kdir + g*8;
            #pragma unroll
            for (int nt = 0; nt < 4; ++nt) {
                const int pt = n0 + nt*16 + c;
                bf16x8 r;
                #pragma unroll
                for (int j = 0; j < 8; ++j) {
                    float vv = fmaxf(fmaf(yprev[(size_t)(ch0 + j) * NPTS + pt],
                                          sc[ch0 + j], sh[ch0 + j]), 0.f);
                    r[j] = (__bf16)vv;
                }
                bf[nt] = r;
            }
        }
        #pragma unroll
        for (int mt = 0; mt < 4; ++mt)
            #pragma unroll
            for (int nt = 0; nt < 4; ++nt)
                acc[mt][nt] = __builtin_amdgcn_mfma_f32_16x16x32_bf16(af[mt], bf[nt], acc[mt][nt], 0, 0, 0);
    }

    #pragma unroll
    for (int mt = 0; mt < 4; ++mt) {
        float s[4], ss[4];
        #pragma unroll
        for (int r = 0; r < 4; ++r) {
            const int o = m0 + mt*16 + g*4 + r;
            const float bv = bias[o];
            float sum = 0.f, sq = 0.f;
            #pragma unroll
            for (int nt = 0; nt < 4; ++nt) {
                float v = acc[mt][nt][r] + bv;
                yout[(size_t)o * NPTS + n0 + nt*16 + c] = v;
                sum += v; sq += v * v;
            }
            s[r] = sum; ss[r] = sq;
        }
        #pragma unroll
        for (int mask = 1; mask <= 8; mask <<= 1)
            #pragma unroll
            for (int r = 0; r < 4; ++r) {
                s[r]  += __shfl_xor(s[r],  mask);
                ss[r] += __shfl_xor(ss[r], mask);
            }
        if (c == 0) {
            #pragma unroll
            for (int r = 0; r < 4; ++r) {
                const int o = m0 + mt*16 + g*4 + r;
                atomicAdd(&stout[o], s[r]);
                atomicAdd(&stout[M + o], ss[r]);
            }
        }
    }
}

// ---------------- final BN + ReLU (in place on d_out), float4-vectorized ----------------
__global__ __launch_bounds__(256) void bnrelu_kernel(
    const float4* y, const float* __restrict__ st,
    const float* __restrict__ g, const float* __restrict__ b,
    float4* out, int C)
{
    int idx = blockIdx.x * 256 + threadIdx.x;   // float4 index
    int c = idx >> 11;   // N/4 = 2048 float4 per channel row
    float mu  = st[c] * (1.f / 8192.f);
    float var = st[C + c] * (1.f / 8192.f) - mu * mu;
    float scale = g[c] / sqrtf(var + 1e-5f);
    float sh = b[c] - mu * scale;
    float4 v = y[idx];
    v.x = fmaxf(fmaf(v.x, scale, sh), 0.f);
    v.y = fmaxf(fmaf(v.y, scale, sh), 0.f);
    v.z = fmaxf(fmaf(v.z, scale, sh), 0.f);
    v.w = fmaxf(fmaf(v.w, scale, sh), 0.f);
    out[idx] = v;
}

extern "C" void kernel_launch(void* const* d_in, const int* in_sizes, int n_in,
                              void* d_out, int out_size, void* d_ws, size_t ws_size,
                              hipStream_t stream) {
    const float* points = (const float*)d_in[0];
    const float* gw0 = (const float*)d_in[1];
    const float* gw1 = (const float*)d_in[2];
    const float* gw2 = (const float*)d_in[3];
    const float* gw3 = (const float*)d_in[4];
    const float* gw4 = (const float*)d_in[5];
    const float* c1w = (const float*)d_in[6];  const float* c1b = (const float*)d_in[7];
    const float* bn1g = (const float*)d_in[8]; const float* bn1b = (const float*)d_in[9];
    const float* c2w = (const float*)d_in[10]; const float* c2b = (const float*)d_in[11];
    const float* bn2g = (const float*)d_in[12];const float* bn2b = (const float*)d_in[13];
    const float* c3w = (const float*)d_in[14]; const float* c3b = (const float*)d_in[15];
    const float* bn3g = (const float*)d_in[16];const float* bn3b = (const float*)d_in[17];
    const float* c4w = (const float*)d_in[18]; const float* c4b = (const float*)d_in[19];
    const float* bn4g = (const float*)d_in[20];const float* bn4b = (const float*)d_in[21];

    float* ws = (float*)d_ws;
    float* p4f    = ws + OFF_P4;
    float* featup = ws + OFF_FEATUP;
    float* y2 = ws + OFF_Y2; float* y3 = ws + OFF_Y3;
    float* s1 = ws + OFF_STATS + 0;
    float* s2 = ws + OFF_STATS + 128;
    float* s3 = ws + OFF_STATS + 384;
    float* s4 = ws + OFF_STATS + 896;
    const unsigned short* gwt = (const unsigned short*)(ws + OFF_GWT);
    const unsigned short* bw2 = (const unsigned short*)(ws + OFF_BW2);
    const unsigned short* bw3 = (const unsigned short*)(ws + OFF_BW3);
    const unsigned short* bw4 = (const unsigned short*)(ws + OFF_BW4);
    unsigned short* xb3v = (unsigned short*)(ws + OFF_XB3V);
    float* outp = (float*)d_out;

    // zero shell cursors (65 u32) — stream-ordered, graph-capture-safe
    hipMemsetAsync(ws + OFF_C, 0, 65 * sizeof(unsigned), stream);

    prepwt_kernel<<<256, 256, 0, stream>>>(points, c1w, c2w, c3w, c4w,
                                           gw0, gw1, gw2, gw3, gw4, ws);

    // knn (radial-shell pruned, direct-scattered segments) + feat_up + feat_down
    knn_feat_kernel<<<1024, 512, 0, stream>>>((const float4*)p4f,
                                              (const float4*)(ws + OFF_P4S),
                                              (const unsigned*)(ws + OFF_IDXS),
                                              (const float4*)(ws + OFF_OVF4),
                                              (const unsigned*)(ws + OFF_OVFI),
                                              (float4*)featup, ws);
    // mlp + conv1-stats side-job (blocks 0..63)
    mlp_kernel<<<2048, 256, 0, stream>>>((const float4*)featup, gwt, xb3v, c1b, ws);

    // conv2 with conv1+BN1 on the fly (XCD-swizzled): -> y2 + s2
    conv2fd_kernel<<<64, 256, 0, stream>>>(bw2, c1b, s1, bn1g, bn1b,
                                           c2b, y2, s2, ws);
    // conv3 (XCD-swizzled): cols 0..63 from xb3v, cols 64..191 = BN2(y2)
    convbn_kernel<<<128, 256, 0, stream>>>(bw3, xb3v, 64, y2, s2, bn2g, bn2b,
                                           c3b, 192, 256, y3, s3);
    // conv4 (XCD-swizzled) with BN3 on the fly -> d_out channel-major (pre-BN4) + s4
    convbn_kernel<<<512, 256, 0, stream>>>(bw4, nullptr, 0, y3, s3, bn3g, bn3b,
                                           c4b, 256, 1024, outp, s4);
    // final BN4 + ReLU in place
    bnrelu_kernel<<<8192, 256, 0, stream>>>((const float4*)outp, s4, bn4g, bn4b, (float4*)outp, 1024);
}

// Round 18
// 320.535 us; speedup vs baseline: 1.0367x; 1.0329x over previous
//
#include <hip/hip_runtime.h>
#include <hip/hip_bf16.h>

#define NPTS 8192
#define KNN 64
#define EPSF 1e-7f

// ---------------- workspace layout (float offsets) ----------------
#define OFF_P4      0              // packed (x,y,z,rr) float4 per point: 4*N
#define OFF_STATS   32768          // s1:+0(128) s2:+128(256) s3:+384(512) s4:+896(2048) = 2944
#define OFF_PART    36012          // 32 blocks x 2 u64 = 128 floats
#define OFF_FEATDN  36864          // N*4 -> 69632 (raw-view source for conv1-on-the-fly)
#define OFF_WT1     69632          // 4*64 fp32 transposed -> 69888
#define OFF_GWT     69888          // MLP bf16 weights: 18432 shorts = 9216 -> 79104
#define OFF_BW2     79104          // c2w bf16: 8192 shorts = 4096 -> 83200
#define OFF_BW3     83200          // c3w bf16: 49152 shorts = 24576 -> 107776
#define OFF_BW4     107776         // c4w bf16: 262144 shorts = 131072 -> 238848
#define OFF_XB3V    238848         // bf16 raw-view emb_up [8192][64] = 262144 fl -> 500992
#define OFF_Y2      2860288        // 128*N fp32 channel-major -> 3908864
#define OFF_Y3      3908864        // 256*N fp32 channel-major -> 6006016
#define OFF_FEATUP  6006016        // N*K*4 fp32 -> 8103168 (~30.9 MB)

typedef __bf16 bf16x8 __attribute__((ext_vector_type(8)));
typedef float  f32x4  __attribute__((ext_vector_type(4)));

__device__ __forceinline__ unsigned f2u(float f) {
    unsigned u = __float_as_uint(f);
    return ((int)u >= 0) ? (u | 0x80000000u) : ~u;
}
__device__ __forceinline__ float key_to_f(unsigned long long k) {
    unsigned v = (unsigned)(k >> 32);
    unsigned ob = (v & 0x80000000u) ? (v ^ 0x80000000u) : ~v;
    return __uint_as_float(ob);
}
// native RNE f32->bf16
__device__ __forceinline__ unsigned short f2bf(float x) {
    union { __bf16 h; unsigned short s; } u;
    u.h = (__bf16)x;
    return u.s;
}
__device__ __forceinline__ unsigned packbf2(float lo, float hi) {
    return (unsigned)f2bf(lo) | ((unsigned)f2bf(hi) << 16);
}
__device__ __forceinline__ unsigned long long u64min(unsigned long long a, unsigned long long b){ return a < b ? a : b; }
__device__ __forceinline__ unsigned long long u64max(unsigned long long a, unsigned long long b){ return a < b ? b : a; }

__device__ __forceinline__ unsigned long long sort_merge(
    unsigned long long key, unsigned long long cur, int lane)
{
    #pragma unroll
    for (int k = 2; k <= 64; k <<= 1) {
        #pragma unroll
        for (int j = k >> 1; j > 0; j >>= 1) {
            unsigned long long o = __shfl_xor(key, j);
            bool up = ((lane & k) == 0);
            bool lower = ((lane & j) == 0);
            key = (lower == up) ? u64min(key, o) : u64max(key, o);
        }
    }
    unsigned long long rev = __shfl(key, 63 - lane);
    unsigned long long m = u64min(cur, rev);
    #pragma unroll
    for (int j = 32; j > 0; j >>= 1) {
        unsigned long long o = __shfl_xor(m, j);
        m = ((lane & j) == 0) ? u64min(m, o) : u64max(m, o);
    }
    return m;
}

// ---------------- prep A + weight prep (fused; disjoint work) ----------------
__global__ __launch_bounds__(256) void prepwt_kernel(
    const float* __restrict__ points,
    const float* __restrict__ c1w, const float* __restrict__ c2w,
    const float* __restrict__ c3w, const float* __restrict__ c4w,
    const float* __restrict__ gw0, const float* __restrict__ gw1,
    const float* __restrict__ gw2, const float* __restrict__ gw3,
    const float* __restrict__ gw4,
    float* __restrict__ ws)
{
    const int t = blockIdx.x * 256 + threadIdx.x;
    const int T = 256 * 256;
    for (int m = t; m < 2944; m += T) ws[OFF_STATS + m] = 0.f;
    for (int m = t; m < 64*4; m += T) { int o = m >> 2, c = m & 3; ws[OFF_WT1 + c*64 + o] = c1w[m]; }

    unsigned short* bw2 = (unsigned short*)(ws + OFF_BW2);
    for (int m = t; m < 128*64; m += T)   bw2[m] = f2bf(c2w[m]);
    unsigned short* bw3 = (unsigned short*)(ws + OFF_BW3);
    for (int m = t; m < 256*192; m += T)  bw3[m] = f2bf(c3w[m]);
    unsigned short* bw4 = (unsigned short*)(ws + OFF_BW4);
    for (int m = t; m < 1024*256; m += T) bw4[m] = f2bf(c4w[m]);

    unsigned short* gwt = (unsigned short*)(ws + OFF_GWT);
    for (int m = t; m < 2048; m += T) {          // gw0T padded [64][32]
        int o = m >> 5, i = m & 31;
        gwt[m] = (i < 4) ? f2bf(gw0[i*64 + o]) : (unsigned short)0;
    }
    const float* gsrc[4] = {gw1, gw2, gw3, gw4};
    for (int l = 0; l < 4; ++l) {
        const float* g = gsrc[l];
        unsigned short* dst = gwt + 2048 + l*4096;
        for (int m = t; m < 4096; m += T) { int o = m >> 6, i = m & 63; dst[m] = f2bf(g[i*64 + o]); }
    }

    // ---- prep_a part (blocks 0..31 only; block-uniform branch) ----
    if (blockIdx.x < 32) {
        const int n = blockIdx.x * 256 + threadIdx.x;
        float x = points[3*n+0], y = points[3*n+1], z = points[3*n+2];
        float rr = x*x + y*y + z*z;
        ((float4*)(ws + OFF_P4))[n] = make_float4(x, y, z, rr);
        float vn = sqrtf(rr);
        unsigned b = __float_as_uint(vn);
        unsigned long long mxk = ((unsigned long long)b << 32) | (unsigned long long)(0xFFFFFFFFu - (unsigned)n);
        unsigned long long mnk = ((unsigned long long)b << 32) | (unsigned long long)(unsigned)n;
        for (int j = 32; j > 0; j >>= 1) {
            mxk = u64max(mxk, __shfl_xor(mxk, j));
            mnk = u64min(mnk, __shfl_xor(mnk, j));
        }
        __shared__ unsigned long long smx[4], smn[4];
        int wid = threadIdx.x >> 6;
        if ((threadIdx.x & 63) == 0) { smx[wid] = mxk; smn[wid] = mnk; }
        __syncthreads();
        if (threadIdx.x == 0) {
            unsigned long long MX = 0ull, MN = ~0ull;
            for (int i = 0; i < 4; ++i) { MX = u64max(MX, smx[i]); MN = u64min(MN, smn[i]); }
            unsigned long long* parts = (unsigned long long*)(ws + OFF_PART);
            parts[2*blockIdx.x + 0] = MX;
            parts[2*blockIdx.x + 1] = MN;
        }
    }
}

// ---------------- KNN + local rotation-invariant features + feat_down ----------------
// 1 query per wave, 8 waves/block, LDS exactly 40960 B -> 4 blocks/CU (160 KiB exact fit).
__global__ __launch_bounds__(512) void knn_feat_kernel(
    const float4* __restrict__ p4, float4* __restrict__ feat_up,
    float* __restrict__ ws)
{
    __shared__ __align__(16) float4 scand[2048];
    __shared__ unsigned long long queue[8][128];
    const int lane = threadIdx.x & 63;
    const int wid  = threadIdx.x >> 6;
    const int q = blockIdx.x * 8 + wid;

    const float4 qa = p4[q];
    unsigned long long cur = ~0ull;
    float ke = __builtin_inff();
    int qc = 0;
    unsigned long long* Q = queue[wid];

    for (int base = 0; base < NPTS; base += 2048) {
        __syncthreads();
        for (int t = threadIdx.x; t < 2048; t += 512) scand[t] = p4[base + t];
        __syncthreads();
        #pragma unroll 2
        for (int sub = 0; sub < 2048; sub += 128) {
            float4 cd0 = scand[sub + lane];
            float4 cd1 = scand[sub + 64 + lane];
            float dot0 = fmaf(qa.x, cd0.x, fmaf(qa.y, cd0.y, qa.z * cd0.z));
            float dot1 = fmaf(qa.x, cd1.x, fmaf(qa.y, cd1.y, qa.z * cd1.z));
            float e0 = fmaf(-2.f, dot0, cd0.w);
            float e1 = fmaf(-2.f, dot1, cd1.w);
            bool p0 = e0 < ke;
            bool p1 = e1 < ke;
            unsigned long long m0 = __ballot(p0);
            unsigned long long m1 = __ballot(p1);
            if (m0) {
                int prefix = __builtin_amdgcn_mbcnt_hi((unsigned)(m0 >> 32),
                              __builtin_amdgcn_mbcnt_lo((unsigned)m0, 0));
                if (p0) Q[qc + prefix] = ((unsigned long long)f2u(e0) << 32)
                                       | (unsigned long long)(unsigned)(base + sub + lane);
                qc += __popcll(m0);
                if (qc >= 64) {
                    qc -= 64;
                    cur = sort_merge(Q[qc + lane], cur, lane);
                    ke = key_to_f(__shfl(cur, 63));
                }
            }
            if (m1) {
                int prefix = __builtin_amdgcn_mbcnt_hi((unsigned)(m1 >> 32),
                              __builtin_amdgcn_mbcnt_lo((unsigned)m1, 0));
                if (p1) Q[qc + prefix] = ((unsigned long long)f2u(e1) << 32)
                                       | (unsigned long long)(unsigned)(base + sub + 64 + lane);
                qc += __popcll(m1);
                if (qc >= 64) {
                    qc -= 64;
                    cur = sort_merge(Q[qc + lane], cur, lane);
                    ke = key_to_f(__shfl(cur, 63));
                }
            }
        }
    }
    cur = sort_merge((lane < qc) ? Q[lane] : ~0ull, cur, lane);

    // feature epilogue (feat_up)
    int nidx = (int)(unsigned)(cur & 0xFFFFFFFFu);
    float4 np = p4[nidx];
    float ox = __shfl(np.x, 0), oy = __shfl(np.y, 0), oz = __shfl(np.z, 0);
    float pcx = np.x - ox, pcy = np.y - oy, pcz = np.z - oz;
    float vn = sqrtf(pcx*pcx + pcy*pcy + pcz*pcz);

    unsigned long long ak = ((unsigned long long)__float_as_uint(vn) << 32)
                          | (unsigned long long)(unsigned)(63 - lane);
    for (int s = 32; s > 0; s >>= 1) ak = u64max(ak, __shfl_xor(ak, s));
    int id1 = 63 - (int)(unsigned)(ak & 0xFFFFFFFFu);

    float a1x = __shfl(pcx, id1), a1y = __shfl(pcy, id1), a1z = __shfl(pcz, id1);
    float n1 = sqrtf(a1x*a1x + a1y*a1y + a1z*a1z) + EPSF;
    a1x /= n1; a1y /= n1; a1z /= n1;

    float sx = pcx, sy = pcy, sz = pcz;
    for (int s = 32; s > 0; s >>= 1) {
        sx += __shfl_xor(sx, s); sy += __shfl_xor(sy, s); sz += __shfl_xor(sz, s);
    }
    float a2x = sx * (1.f/64.f), a2y = sy * (1.f/64.f), a2z = sz * (1.f/64.f);
    float n2 = sqrtf(a2x*a2x + a2y*a2y + a2z*a2z) + EPSF;
    a2x /= n2; a2y /= n2; a2z /= n2;

    float a3x = a1x + 1.5f*a2x, a3y = a1y + 1.5f*a2y, a3z = a1z + 1.5f*a2z;
    float n3 = sqrtf(a3x*a3x + a3y*a3y + a3z*a3z) + EPSF;
    a3x /= n3; a3y /= n3; a3z /= n3;

    float den = vn + EPSF;
    float f1 = (pcx*a1x + pcy*a1y + pcz*a1z) / den;
    float f2 = (pcx*a2x + pcy*a2y + pcz*a2z) / den;
    float f3 = (pcx*a3x + pcy*a3y + pcz*a3z) / den;
    feat_up[q*64 + lane] = make_float4(f1, f2, f3, vn);

    // feat_down (prep_c folded): per-wave parts-reduce in registers, lane 0 writes.
    {
        const unsigned long long* parts = (const unsigned long long*)(ws + OFF_PART);
        unsigned long long mxk = (lane < 32) ? parts[2*lane + 0] : 0ull;
        unsigned long long mnk = (lane < 32) ? parts[2*lane + 1] : ~0ull;
        for (int s = 32; s > 0; s >>= 1) {
            mxk = u64max(mxk, __shfl_xor(mxk, s));
            mnk = u64min(mnk, __shfl_xor(mnk, s));
        }
        if (lane == 0) {
            int i1 = (int)(0xFFFFFFFFu - (unsigned)(mxk & 0xFFFFFFFFu));
            int i2 = (int)(unsigned)(mnk & 0xFFFFFFFFu);
            float4 p1 = p4[i1];
            float4 p2 = p4[i2];
            float w1 = sqrtf(p1.x*p1.x + p1.y*p1.y + p1.z*p1.z) + EPSF;
            float b1x = p1.x/w1, b1y = p1.y/w1, b1z = p1.z/w1;
            float w2 = sqrtf(p2.x*p2.x + p2.y*p2.y + p2.z*p2.z) + EPSF;
            float b2x = p2.x/w2, b2y = p2.y/w2, b2z = p2.z/w2;
            float b3x = b1x + 1.5f*b2x, b3y = b1y + 1.5f*b2y, b3z = b1z + 1.5f*b2z;
            float w3 = sqrtf(b3x*b3x + b3y*b3y + b3z*b3z) + EPSF;
            b3x /= w3; b3y /= w3; b3z /= w3;
            float vq = sqrtf(qa.w);
            float dq = vq + EPSF;
            float g1 = (qa.x*b1x + qa.y*b1y + qa.z*b1z) / dq;
            float g2 = (qa.x*b2x + qa.y*b2y + qa.z*b2z) / dq;
            float g3 = (qa.x*b3x + qa.y*b3y + qa.z*b3z) / dq;
            ((float4*)(ws + OFF_FEATDN))[q] = make_float4(g1, g2, g3, vq);
        }
    }
}

// ---------------- 5-layer MLP via bf16 MFMA + max over K + conv1-STATS side-job ----------------
#define BROW 72
__global__ __launch_bounds__(256) void mlp_kernel(
    const float4* __restrict__ feat_up,
    const unsigned short* __restrict__ gwt,
    unsigned short* __restrict__ xb3v,
    const float* __restrict__ c1b,
    float* __restrict__ ws)
{
    __shared__ __align__(16) unsigned short Blds[4][64 * BROW];
    const int lane = threadIdx.x & 63;
    const int wid  = threadIdx.x >> 6;
    const int q = blockIdx.x * 4 + wid;
    const int c = lane & 15, g = lane >> 4;
    unsigned short* B = Blds[wid];

    {
        float4 f = feat_up[q*64 + lane];
        uint2 p0;
        p0.x = packbf2(f.x, f.y);
        p0.y = packbf2(f.z, f.w);
        *(uint2*)&B[lane*BROW] = p0;
        *(uint2*)&B[lane*BROW + 4] = make_uint2(0, 0);
        uint4 z4 = make_uint4(0, 0, 0, 0);
        *(uint4*)&B[lane*BROW + 8]  = z4;
        *(uint4*)&B[lane*BROW + 16] = z4;
        *(uint4*)&B[lane*BROW + 24] = z4;
    }

    const unsigned short* Wl[5] = {gwt, gwt + 2048, gwt + 6144, gwt + 10240, gwt + 14336};
    f32x4 acc[4][4];

    for (int layer = 0; layer < 5; ++layer) {
        const int wstride = (layer == 0) ? 32 : 64;
        const int nks = (layer == 0) ? 1 : 2;
        #pragma unroll
        for (int mb = 0; mb < 4; ++mb)
            #pragma unroll
            for (int nb = 0; nb < 4; ++nb)
                acc[mb][nb] = (f32x4){0.f, 0.f, 0.f, 0.f};

        for (int ks = 0; ks < nks; ++ks) {
            bf16x8 af[4], bf[4];
            #pragma unroll
            for (int mb = 0; mb < 4; ++mb)
                af[mb] = *(const bf16x8*)(Wl[layer] + (mb*16 + c)*wstride + ks*32 + g*8);
            #pragma unroll
            for (int nb = 0; nb < 4; ++nb)
                bf[nb] = *(const bf16x8*)&B[(nb*16 + c)*BROW + ks*32 + g*8];
            #pragma unroll
            for (int mb = 0; mb < 4; ++mb)
                #pragma unroll
                for (int nb = 0; nb < 4; ++nb)
                    acc[mb][nb] = __builtin_amdgcn_mfma_f32_16x16x32_bf16(af[mb], bf[nb], acc[mb][nb], 0, 0, 0);
        }

        if (layer < 4) {
            #pragma unroll
            for (int mb = 0; mb < 4; ++mb) {
                #pragma unroll
                for (int nb = 0; nb < 4; ++nb) {
                    f32x4 a = acc[mb][nb];
                    uint2 pw;
                    pw.x = packbf2(fmaxf(a[0], 0.f), fmaxf(a[1], 0.f));
                    pw.y = packbf2(fmaxf(a[2], 0.f), fmaxf(a[3], 0.f));
                    *(uint2*)&B[(nb*16 + c)*BROW + mb*16 + g*4] = pw;
                }
            }
        }
    }

    // epilogue: ReLU + max over neighbors; write raw-view array
    const int cc = q >> 7;
    const int pbase = (q & 127) << 6;
    #pragma unroll
    for (int mb = 0; mb < 4; ++mb) {
        float v[4];
        #pragma unroll
        for (int r = 0; r < 4; ++r)
            v[r] = fmaxf(fmaxf(fmaxf(acc[mb][0][r], acc[mb][1][r]),
                               fmaxf(acc[mb][2][r], acc[mb][3][r])), 0.f);
        #pragma unroll
        for (int mask = 1; mask <= 8; mask <<= 1)
            #pragma unroll
            for (int r = 0; r < 4; ++r)
                v[r] = fmaxf(v[r], __shfl_xor(v[r], mask));
        if (c == 0) {
            #pragma unroll
            for (int r = 0; r < 4; ++r) {
                const int f = mb*16 + g*4 + r;
                xb3v[(size_t)(pbase + f) * 64 + cc] = f2bf(v[r]);
            }
        }
    }

    // ---- conv1-stats side-job (blocks 0..63; block-uniform branch) ----
    if (blockIdx.x < 64) {
        __syncthreads();                          // all waves done with Blds
        float* sps  = (float*)&Blds[0][0];        // overlay: ps[4][32]
        float* spss = sps + 128;                  //          pss[4][32]
        const int tid = threadIdx.x;
        const int bx = blockIdx.x & 31, by = blockIdx.x >> 5;
        const int p  = bx * 256 + tid;
        const int o0 = by * 32;
        const float* fdn = ws + OFF_FEATDN;       // flat raw-view
        const float* wt1 = ws + OFF_WT1;
        float* s1 = ws + OFF_STATS;
        float xv0 = fdn[p], xv1 = fdn[8192 + p], xv2 = fdn[16384 + p], xv3 = fdn[24576 + p];
        float accc[32];
        #pragma unroll
        for (int u = 0; u < 32; ++u) accc[u] = c1b[o0 + u];
        #pragma unroll
        for (int u = 0; u < 32; ++u) accc[u] = fmaf(xv0, wt1[0*64 + o0 + u], accc[u]);
        #pragma unroll
        for (int u = 0; u < 32; ++u) accc[u] = fmaf(xv1, wt1[1*64 + o0 + u], accc[u]);
        #pragma unroll
        for (int u = 0; u < 32; ++u) accc[u] = fmaf(xv2, wt1[2*64 + o0 + u], accc[u]);
        #pragma unroll
        for (int u = 0; u < 32; ++u) accc[u] = fmaf(xv3, wt1[3*64 + o0 + u], accc[u]);
        #pragma unroll
        for (int u = 0; u < 32; ++u) {
            float s = accc[u], ss = accc[u] * accc[u];
            for (int j = 32; j > 0; j >>= 1) { s += __shfl_xor(s, j); ss += __shfl_xor(ss, j); }
            if (lane == 0) { sps[wid*32 + u] = s; spss[wid*32 + u] = ss; }
        }
        __syncthreads();
        if (tid < 32) {
            float S  = sps[tid] + sps[32 + tid] + sps[64 + tid] + sps[96 + tid];
            float SS = spss[tid] + spss[32 + tid] + spss[64 + tid] + spss[96 + tid];
            atomicAdd(&s1[o0 + tid], S);
            atomicAdd(&s1[64 + o0 + tid], SS);
        }
    }
}

// XCD-aware bijective block swizzle (T1). nwg % 8 == 0 required (64/128/512 ok).
__device__ __forceinline__ void xcd_tile(int nwg, int MB, int& nb, int& mb) {
    const int bid = blockIdx.x;
    const int bidp = (bid & 7) * (nwg >> 3) + (bid >> 3);
    mb = bidp % MB;
    nb = bidp / MB;
}

// ---------------- conv2fd: conv2 MFMA with conv1+BN1+ReLU+bf16 built on the fly ----------------
__global__ __launch_bounds__(256) void conv2fd_kernel(
    const unsigned short* __restrict__ A,
    const float* __restrict__ c1b,
    const float* __restrict__ stp, const float* __restrict__ gam, const float* __restrict__ bet,
    const float* __restrict__ bias, float* __restrict__ yout, float* __restrict__ stout,
    const float* __restrict__ ws)
{
    __shared__ float sc[64], sh[64], swt[256], sb[64];
    const int tid = threadIdx.x;
    if (tid < 64) {
        float mu  = stp[tid] * (1.f / 8192.f);
        float var = stp[64 + tid] * (1.f / 8192.f) - mu * mu;
        float s = gam[tid] / sqrtf(var + 1e-5f);
        sc[tid] = s; sh[tid] = bet[tid] - mu * s;
        sb[tid] = c1b[tid];
    }
    if (tid < 256) swt[tid] = ws[OFF_WT1 + tid];
    __syncthreads();

    const float* fdn = ws + OFF_FEATDN;
    const int lane = tid & 63;
    const int w = tid >> 6;
    int nb, mb;
    xcd_tile(64, 2, nb, mb);
    const int n0 = nb * 256 + w * 64;
    const int m0 = mb * 64;
    const int c = lane & 15, g = lane >> 4;
    const int K = 64, M = 128;

    f32x4 acc[4][4];
    #pragma unroll
    for (int mt = 0; mt < 4; ++mt)
        #pragma unroll
        for (int nt = 0; nt < 4; ++nt)
            acc[mt][nt] = (f32x4){0.f, 0.f, 0.f, 0.f};

    for (int k0 = 0; k0 < K; k0 += 32) {
        bf16x8 af[4], bf[4];
        #pragma unroll
        for (int mt = 0; mt < 4; ++mt)
            af[mt] = *(const bf16x8*)(A + (size_t)(m0 + mt*16 + c) * K + k0 + g*8);
        const int ch0 = k0 + g*8;
        #pragma unroll
        for (int nt = 0; nt < 4; ++nt) {
            const int pt = n0 + nt*16 + c;
            const float fd0 = fdn[pt];
            const float fd1 = fdn[8192 + pt];
            const float fd2 = fdn[16384 + pt];
            const float fd3 = fdn[24576 + pt];
            bf16x8 r;
            #pragma unroll
            for (int j = 0; j < 8; ++j) {
                const int ch = ch0 + j;
                float v = fmaf(fd3, swt[192 + ch],
                          fmaf(fd2, swt[128 + ch],
                          fmaf(fd1, swt[64 + ch],
                          fmaf(fd0, swt[ch], sb[ch]))));
                r[j] = (__bf16)fmaxf(fmaf(v, sc[ch], sh[ch]), 0.f);
            }
            bf[nt] = r;
        }
        #pragma unroll
        for (int mt = 0; mt < 4; ++mt)
            #pragma unroll
            for (int nt = 0; nt < 4; ++nt)
                acc[mt][nt] = __builtin_amdgcn_mfma_f32_16x16x32_bf16(af[mt], bf[nt], acc[mt][nt], 0, 0, 0);
    }

    #pragma unroll
    for (int mt = 0; mt < 4; ++mt) {
        float s[4], ss[4];
        #pragma unroll
        for (int r = 0; r < 4; ++r) {
            const int o = m0 + mt*16 + g*4 + r;
            const float bv = bias[o];
            float sum = 0.f, sq = 0.f;
            #pragma unroll
            for (int nt = 0; nt < 4; ++nt) {
                float v = acc[mt][nt][r] + bv;
                yout[(size_t)o * NPTS + n0 + nt*16 + c] = v;
                sum += v; sq += v * v;
            }
            s[r] = sum; ss[r] = sq;
        }
        #pragma unroll
        for (int mask = 1; mask <= 8; mask <<= 1)
            #pragma unroll
            for (int r = 0; r < 4; ++r) {
                s[r]  += __shfl_xor(s[r],  mask);
                ss[r] += __shfl_xor(ss[r], mask);
            }
        if (c == 0) {
            #pragma unroll
            for (int r = 0; r < 4; ++r) {
                const int o = m0 + mt*16 + g*4 + r;
                atomicAdd(&stout[o], s[r]);
                atomicAdd(&stout[M + o], ss[r]);
            }
        }
    }
}

// ---------------- convbn: MFMA conv with previous-layer BN+ReLU+bf16 applied on the fly ----------------
__global__ __launch_bounds__(256) void convbn_kernel(
    const unsigned short* __restrict__ A,
    const unsigned short* __restrict__ Bdir, int Kdir,
    const float* __restrict__ yprev,
    const float* __restrict__ stp, const float* __restrict__ gam, const float* __restrict__ bet,
    const float* __restrict__ bias, int K, int M,
    float* __restrict__ yout, float* __restrict__ stout)
{
    __shared__ float sc[256], sh[256];
    const int tid = threadIdx.x;
    const int Cp = K - Kdir;
    for (int cc = tid; cc < Cp; cc += 256) {
        float mu  = stp[cc] * (1.f / 8192.f);
        float var = stp[Cp + cc] * (1.f / 8192.f) - mu * mu;
        float s = gam[cc] / sqrtf(var + 1e-5f);
        sc[cc] = s; sh[cc] = bet[cc] - mu * s;
    }
    __syncthreads();

    const int lane = tid & 63;
    const int w = tid >> 6;
    int nb, mb;
    xcd_tile(gridDim.x, M >> 6, nb, mb);
    const int n0 = nb * 256 + w * 64;
    const int m0 = mb * 64;
    const int c = lane & 15, g = lane >> 4;

    f32x4 acc[4][4];
    #pragma unroll
    for (int mt = 0; mt < 4; ++mt)
        #pragma unroll
        for (int nt = 0; nt < 4; ++nt)
            acc[mt][nt] = (f32x4){0.f, 0.f, 0.f, 0.f};

    for (int k0 = 0; k0 < K; k0 += 32) {
        bf16x8 af[4], bf[4];
        #pragma unroll
        for (int mt = 0; mt < 4; ++mt)
            af[mt] = *(const bf16x8*)(A + (size_t)(m0 + mt*16 + c) * K + k0 + g*8);
        if (k0 + 32 <= Kdir) {
            #pragma unroll
            for (int nt = 0; nt < 4; ++nt)
                bf[nt] = *(const bf16x8*)(Bdir + (size_t)(n0 + nt*16 + c) * Kdir + k0 + g*8);
        } else {
            const int ch0 = k0 - Kdir + g*8;
            #pragma unroll
            for (int nt = 0; nt < 4; ++nt) {
                const int pt = n0 + nt*16 + c;
                bf16x8 r;
                #pragma unroll
                for (int j = 0; j < 8; ++j) {
                    float vv = fmaxf(fmaf(yprev[(size_t)(ch0 + j) * NPTS + pt],
                                          sc[ch0 + j], sh[ch0 + j]), 0.f);
                    r[j] = (__bf16)vv;
                }
                bf[nt] = r;
            }
        }
        #pragma unroll
        for (int mt = 0; mt < 4; ++mt)
            #pragma unroll
            for (int nt = 0; nt < 4; ++nt)
                acc[mt][nt] = __builtin_amdgcn_mfma_f32_16x16x32_bf16(af[mt], bf[nt], acc[mt][nt], 0, 0, 0);
    }

    #pragma unroll
    for (int mt = 0; mt < 4; ++mt) {
        float s[4], ss[4];
        #pragma unroll
        for (int r = 0; r < 4; ++r) {
            const int o = m0 + mt*16 + g*4 + r;
            const float bv = bias[o];
            float sum = 0.f, sq = 0.f;
            #pragma unroll
            for (int nt = 0; nt < 4; ++nt) {
                float v = acc[mt][nt][r] + bv;
                yout[(size_t)o * NPTS + n0 + nt*16 + c] = v;
                sum += v; sq += v * v;
            }
            s[r] = sum; ss[r] = sq;
        }
        #pragma unroll
        for (int mask = 1; mask <= 8; mask <<= 1)
            #pragma unroll
            for (int r = 0; r < 4; ++r) {
                s[r]  += __shfl_xor(s[r],  mask);
                ss[r] += __shfl_xor(ss[r], mask);
            }
        if (c == 0) {
            #pragma unroll
            for (int r = 0; r < 4; ++r) {
                const int o = m0 + mt*16 + g*4 + r;
                atomicAdd(&stout[o], s[r]);
                atomicAdd(&stout[M + o], ss[r]);
            }
        }
    }
}

// ---------------- final BN + ReLU (in place on d_out), float4-vectorized ----------------
__global__ __launch_bounds__(256) void bnrelu_kernel(
    const float4* y, const float* __restrict__ st,
    const float* __restrict__ g, const float* __restrict__ b,
    float4* out, int C)
{
    int idx = blockIdx.x * 256 + threadIdx.x;   // float4 index
    int c = idx >> 11;   // N/4 = 2048 float4 per channel row
    float mu  = st[c] * (1.f / 8192.f);
    float var = st[C + c] * (1.f / 8192.f) - mu * mu;
    float scale = g[c] / sqrtf(var + 1e-5f);
    float sh = b[c] - mu * scale;
    float4 v = y[idx];
    v.x = fmaxf(fmaf(v.x, scale, sh), 0.f);
    v.y = fmaxf(fmaf(v.y, scale, sh), 0.f);
    v.z = fmaxf(fmaf(v.z, scale, sh), 0.f);
    v.w = fmaxf(fmaf(v.w, scale, sh), 0.f);
    out[idx] = v;
}

extern "C" void kernel_launch(void* const* d_in, const int* in_sizes, int n_in,
                              void* d_out, int out_size, void* d_ws, size_t ws_size,
                              hipStream_t stream) {
    const float* points = (const float*)d_in[0];
    const float* gw0 = (const float*)d_in[1];
    const float* gw1 = (const float*)d_in[2];
    const float* gw2 = (const float*)d_in[3];
    const float* gw3 = (const float*)d_in[4];
    const float* gw4 = (const float*)d_in[5];
    const float* c1w = (const float*)d_in[6];  const float* c1b = (const float*)d_in[7];
    const float* bn1g = (const float*)d_in[8]; const float* bn1b = (const float*)d_in[9];
    const float* c2w = (const float*)d_in[10]; const float* c2b = (const float*)d_in[11];
    const float* bn2g = (const float*)d_in[12];const float* bn2b = (const float*)d_in[13];
    const float* c3w = (const float*)d_in[14]; const float* c3b = (const float*)d_in[15];
    const float* bn3g = (const float*)d_in[16];const float* bn3b = (const float*)d_in[17];
    const float* c4w = (const float*)d_in[18]; const float* c4b = (const float*)d_in[19];
    const float* bn4g = (const float*)d_in[20];const float* bn4b = (const float*)d_in[21];

    float* ws = (float*)d_ws;
    float* p4f    = ws + OFF_P4;
    float* featup = ws + OFF_FEATUP;
    float* y2 = ws + OFF_Y2; float* y3 = ws + OFF_Y3;
    float* s1 = ws + OFF_STATS + 0;
    float* s2 = ws + OFF_STATS + 128;
    float* s3 = ws + OFF_STATS + 384;
    float* s4 = ws + OFF_STATS + 896;
    const unsigned short* gwt = (const unsigned short*)(ws + OFF_GWT);
    const unsigned short* bw2 = (const unsigned short*)(ws + OFF_BW2);
    const unsigned short* bw3 = (const unsigned short*)(ws + OFF_BW3);
    const unsigned short* bw4 = (const unsigned short*)(ws + OFF_BW4);
    unsigned short* xb3v = (unsigned short*)(ws + OFF_XB3V);
    float* outp = (float*)d_out;

    prepwt_kernel<<<256, 256, 0, stream>>>(points, c1w, c2w, c3w, c4w,
                                           gw0, gw1, gw2, gw3, gw4, ws);

    // knn + feat_up + feat_down (prep_c folded, register-only)
    knn_feat_kernel<<<1024, 512, 0, stream>>>((const float4*)p4f, (float4*)featup, ws);
    // mlp + conv1-stats side-job (blocks 0..63)
    mlp_kernel<<<2048, 256, 0, stream>>>((const float4*)featup, gwt, xb3v, c1b, ws);

    // conv2 with conv1+BN1 on the fly (XCD-swizzled): -> y2 + s2
    conv2fd_kernel<<<64, 256, 0, stream>>>(bw2, c1b, s1, bn1g, bn1b,
                                           c2b, y2, s2, ws);
    // conv3 (XCD-swizzled): cols 0..63 from xb3v, cols 64..191 = BN2(y2)
    convbn_kernel<<<128, 256, 0, stream>>>(bw3, xb3v, 64, y2, s2, bn2g, bn2b,
                                           c3b, 192, 256, y3, s3);
    // conv4 (XCD-swizzled) with BN3 on the fly -> d_out channel-major (pre-BN4) + s4
    convbn_kernel<<<512, 256, 0, stream>>>(bw4, nullptr, 0, y3, s3, bn3g, bn3b,
                                           c4b, 256, 1024, outp, s4);
    // final BN4 + ReLU in place
    bnrelu_kernel<<<8192, 256, 0, stream>>>((const float4*)outp, s4, bn4g, bn4b, (float4*)outp, 1024);
}